// Round 2
// baseline (1102.312 us; speedup 1.0000x reference)
//
#include <hip/hip_runtime.h>
#include <hip/hip_bf16.h>

#define NND 2048
#define BBATCH 4
#define SS 1024
#define SFZ 384
#define IFZ 256
#define HH 8
#define AA 64
#define HA 512

// ---------------------------------------------------------------------------
// Kernel 0: detect actual storage dtype of mask/batch and normalize to int32.
// mask modes: 0=fp32, 1=bf16, 2=u8/bool, 3=int32, 4=int64
// batch: int32 vs int64 (int64 interleave breaks int32 sortedness)
// ---------------------------------------------------------------------------
__global__ void detect_norm(const void* __restrict__ mask_raw,
                            const void* __restrict__ batch_raw,
                            int* __restrict__ mask_i, int* __restrict__ batch_i)
{
    __shared__ int fl[4];
    __shared__ int fb;
    const int t = threadIdx.x;
    if (t < 4) fl[t] = 0;
    if (t == 0) fb = 0;
    __syncthreads();
    const unsigned char*  mb = (const unsigned char*)mask_raw;
    const unsigned short* mh = (const unsigned short*)mask_raw;
    const unsigned int*   mw = (const unsigned int*)mask_raw;
    int f0 = 0, f1 = 0, f2 = 0, f3 = 0;
    // first 4KB is safe to read under every candidate dtype
    for (int i = t; i < 2048; i += 256) {
        unsigned short h = mh[i];
        if (h == 0x3f80u) f0 = 1;                 // a bf16/fp32 "1.0" halfword
        if ((i & 1) == 0 && h != 0) f1 = 1;       // even halfword nonzero
    }
    for (int i = t; i < 4096; i += 256)
        if ((i & 3) != 0 && mb[i] != 0) f2 = 1;   // non-word-aligned byte
    for (int i = t; i < 1024; i += 256)
        if ((i & 1) != 0 && mw[i] != 0) f3 = 1;   // odd int32 word nonzero
    const int* bw = (const int*)batch_raw;
    int f4 = 0;
    for (int i = t + 1; i < 2048; i += 256)
        if (bw[i] < bw[i-1]) f4 = 1;              // int64 interleave breaks sortedness
    if (f0) atomicOr(&fl[0], 1);
    if (f1) atomicOr(&fl[1], 1);
    if (f2) atomicOr(&fl[2], 1);
    if (f3) atomicOr(&fl[3], 1);
    if (f4) atomicOr(&fb, 1);
    __syncthreads();
    int mode;
    if (fl[0])      mode = fl[1] ? 1 : 0;
    else if (fl[2]) mode = 2;
    else if (fl[3]) mode = 3;
    else            mode = 4;
    for (int s = t; s < BBATCH*SS; s += 256) {
        int m;
        switch (mode) {
            case 0:  m = (mw[s]   != 0); break;
            case 1:  m = (mh[s]   != 0); break;
            case 2:  m = (mb[s]   != 0); break;
            case 3:  m = (mw[s]   != 0); break;
            default: m = (mw[2*s] != 0); break;
        }
        mask_i[s] = m;
    }
    const int b64 = fb;
    for (int i = t; i < NND; i += 256)
        batch_i[i] = (b64 ? bw[2*i] : bw[i]) & 3;
}

// ---------------------------------------------------------------------------
// Kernel 1: k = emb@Wk, v = emb@Wv  (rows 4096, cols 512, K=384) -> fp32 ws
// 8 rows per block staged in LDS; thread = one output column.
// ---------------------------------------------------------------------------
__global__ __launch_bounds__(256) void kv_proj(
    const float* __restrict__ emb,
    const float* __restrict__ Wk, const float* __restrict__ Wv,
    float* __restrict__ k_ws, float* __restrict__ v_ws)
{
    __shared__ float e_lds[8 * SFZ];
    const int t   = threadIdx.x;
    const int r0  = blockIdx.y * 8;
    const int col = blockIdx.x * 256 + t;
    const float* ebase = emb + (size_t)r0 * SFZ;
    for (int i = t * 4; i < 8 * SFZ; i += 1024)
        *(float4*)&e_lds[i] = *(const float4*)&ebase[i];
    __syncthreads();
    float ak[8] = {0,0,0,0,0,0,0,0};
    float av[8] = {0,0,0,0,0,0,0,0};
    const float* pk = Wk + col;
    const float* pv = Wv + col;
    for (int kk = 0; kk < SFZ; ++kk) {
        const float wk = pk[(size_t)kk * HA];
        const float wv = pv[(size_t)kk * HA];
        #pragma unroll
        for (int r = 0; r < 8; ++r) {
            const float e = e_lds[r * SFZ + kk];
            ak[r] = fmaf(e, wk, ak[r]);
            av[r] = fmaf(e, wv, av[r]);
        }
    }
    #pragma unroll
    for (int r = 0; r < 8; ++r) {
        k_ws[(size_t)(r0 + r) * HA + col] = ak[r];
        v_ws[(size_t)(r0 + r) * HA + col] = av[r];
    }
}

// ---------------------------------------------------------------------------
// Kernel 2: q = x@Wq, gate = sigmoid(x@Wg + bg)  -> fp32 ws
// ---------------------------------------------------------------------------
__global__ __launch_bounds__(256) void qg_proj(
    const float* __restrict__ x,
    const float* __restrict__ Wq, const float* __restrict__ Wg,
    const float* __restrict__ bg,
    float* __restrict__ q_ws, float* __restrict__ gate_ws)
{
    __shared__ float x_lds[8 * IFZ];
    const int t   = threadIdx.x;
    const int r0  = blockIdx.y * 8;
    const int col = blockIdx.x * 256 + t;
    const float* xbase = x + (size_t)r0 * IFZ;
    for (int i = t * 4; i < 8 * IFZ; i += 1024)
        *(float4*)&x_lds[i] = *(const float4*)&xbase[i];
    __syncthreads();
    float aq[8] = {0,0,0,0,0,0,0,0};
    float ag[8] = {0,0,0,0,0,0,0,0};
    const float* pq = Wq + col;
    const float* pg = Wg + col;
    for (int kk = 0; kk < IFZ; ++kk) {
        const float wq = pq[(size_t)kk * HA];
        const float wg = pg[(size_t)kk * HA];
        #pragma unroll
        for (int r = 0; r < 8; ++r) {
            const float e = x_lds[r * IFZ + kk];
            aq[r] = fmaf(e, wq, aq[r]);
            ag[r] = fmaf(e, wg, ag[r]);
        }
    }
    const float bgv = bg[col];
    #pragma unroll
    for (int r = 0; r < 8; ++r) {
        q_ws[(size_t)(r0 + r) * HA + col]    = aq[r];
        const float z = ag[r] + bgv;
        gate_ws[(size_t)(r0 + r) * HA + col] = 1.f / (1.f + __expf(-z));
    }
}

// ---------------------------------------------------------------------------
// Kernel 3: per-node attention. One block per node.
// scores -> raw logits out -> masked softmax (per-head 32-lane groups) -> feat
// LDS scores layout [s][9] (pad 8->9) keeps all phases conflict-light.
// ---------------------------------------------------------------------------
__global__ __launch_bounds__(256) void attn_kernel(
    const float* __restrict__ k_ws, const float* __restrict__ v_ws,
    const float* __restrict__ q_ws, const int* __restrict__ mask_i,
    const int* __restrict__ batch_i, float* __restrict__ feat_ws,
    float* __restrict__ out_logits)
{
    __shared__ float sc[SS * 9];     // 36 KB
    __shared__ float q_l[HH * 72];   // padded stride 72 (16B-aligned rows)
    __shared__ float m_l[SS];
    const int t = threadIdx.x;
    const int n = blockIdx.x;
    const int b = batch_i[n];
    for (int j = t; j < HA; j += 256)
        q_l[(j >> 6) * 72 + (j & 63)] = q_ws[(size_t)n * HA + j];
    for (int s = t; s < SS; s += 256)
        m_l[s] = (float)mask_i[b * SS + s];
    __syncthreads();
    {
        const int h = t & 7, sl = t >> 3;
        const float4* qf = (const float4*)(&q_l[h * 72]);
        for (int it = 0; it < 32; ++it) {
            const int s = it * 32 + sl;
            const float4* kp = (const float4*)(k_ws + ((size_t)(b * SS + s) * HA + h * AA));
            float acc = 0.f;
            #pragma unroll
            for (int c = 0; c < 16; ++c) {
                const float4 kx = kp[c];
                const float4 q0 = qf[c];
                acc = fmaf(kx.x, q0.x, acc);
                acc = fmaf(kx.y, q0.y, acc);
                acc = fmaf(kx.z, q0.z, acc);
                acc = fmaf(kx.w, q0.w, acc);
            }
            sc[s * 9 + h] = acc * 0.125f;   // /sqrt(A)
        }
    }
    __syncthreads();
    // raw-score logits (pre-mask), heads 0+1
    for (int s = t; s < SS; s += 256)
        out_logits[(size_t)n * SS + s] = sc[s*9] + sc[s*9 + 1];
    // masked softmax: group g (32 lanes) handles head g
    const int g = t >> 5, j = t & 31;
    float smax = -3.402823466e38f;
    for (int s = j; s < SS; s += 32)
        if (m_l[s] > 0.5f) smax = fmaxf(smax, sc[s * 9 + g]);
    #pragma unroll
    for (int off = 16; off >= 1; off >>= 1)
        smax = fmaxf(smax, __shfl_xor(smax, off));
    __syncthreads();   // logits/smax reads must complete before overwrite
    float ssum = 0.f;
    for (int s = j; s < SS; s += 32) {
        const float e = (m_l[s] > 0.5f) ? __expf(sc[s * 9 + g] - smax) : 0.f;
        sc[s * 9 + g] = e;
        ssum += e;
    }
    #pragma unroll
    for (int off = 16; off >= 1; off >>= 1) ssum += __shfl_xor(ssum, off);
    const float inv = 1.f / (ssum + 1e-9f);
    for (int s = j; s < SS; s += 32) sc[s * 9 + g] *= inv;
    __syncthreads();
    // feat[n,h,a] = sum_s w[s,h] * v[b,s,h,a]; thread -> (h, 2 consecutive a)
    const int fh = t >> 5;
    const int a0 = (t & 31) * 2;
    const float* vp = v_ws + (size_t)b * SS * HA + fh * AA + a0;
    float f0 = 0.f, f1 = 0.f;
    #pragma unroll 4
    for (int s = 0; s < SS; ++s) {
        const float w = sc[s * 9 + fh];
        const float2 vv = *(const float2*)(vp + (size_t)s * HA);
        f0 = fmaf(w, vv.x, f0);
        f1 = fmaf(w, vv.y, f1);
    }
    float* fo = feat_ws + (size_t)n * HA + fh * AA + a0;
    fo[0] = f0; fo[1] = f1;
}

// ---------------------------------------------------------------------------
// Kernel 4: new = (gate*feat)@Wback + bback; y = sqrt2*x + new; LayerNorm.
// One block (256 threads) per node; thread = one output channel.
// ---------------------------------------------------------------------------
__global__ __launch_bounds__(256) void back_ln(
    const float* __restrict__ gate_ws, const float* __restrict__ feat_ws,
    const float* __restrict__ x,
    const float* __restrict__ Wback, const float* __restrict__ bback,
    const float* __restrict__ gamma, const float* __restrict__ beta,
    float* __restrict__ out)
{
    __shared__ float gf[HA];
    __shared__ float red[8];
    const int t = threadIdx.x, n = blockIdx.x;
    for (int j = t; j < HA; j += 256)
        gf[j] = gate_ws[(size_t)n * HA + j] * feat_ws[(size_t)n * HA + j];
    __syncthreads();
    float acc = bback[t];
    const float* wb = Wback + t;
    #pragma unroll 4
    for (int jj = 0; jj < HA; ++jj)
        acc = fmaf(gf[jj], wb[(size_t)jj * IFZ], acc);
    const float y = fmaf(1.41421356237309515f, x[(size_t)n * IFZ + t], acc);
    float s1 = y, s2 = y * y;
    #pragma unroll
    for (int off = 32; off >= 1; off >>= 1) {
        s1 += __shfl_xor(s1, off);
        s2 += __shfl_xor(s2, off);
    }
    const int wid = t >> 6, lane = t & 63;
    if (lane == 0) { red[wid] = s1; red[4 + wid] = s2; }
    __syncthreads();
    const float S1 = red[0] + red[1] + red[2] + red[3];
    const float S2 = red[4] + red[5] + red[6] + red[7];
    const float mu  = S1 * (1.f / IFZ);
    const float var = S2 * (1.f / IFZ) - mu * mu;
    const float r   = rsqrtf(var + 1e-5f);
    const float o   = (y - mu) * r * gamma[t] + beta[t];
    out[(size_t)n * IFZ + t] = o;
}

extern "C" void kernel_launch(void* const* d_in, const int* in_sizes, int n_in,
                              void* d_out, int out_size, void* d_ws, size_t ws_size,
                              hipStream_t stream) {
    const float* x     = (const float*)d_in[0];
    const float* emb   = (const float*)d_in[1];
    const void*  mraw  = d_in[2];
    const void*  braw  = d_in[3];
    const float* Wq    = (const float*)d_in[4];
    const float* Wk    = (const float*)d_in[5];
    const float* Wv    = (const float*)d_in[6];
    const float* Wg    = (const float*)d_in[7];
    const float* bg    = (const float*)d_in[8];
    const float* Wback = (const float*)d_in[9];
    const float* bback = (const float*)d_in[10];
    const float* gamma = (const float*)d_in[11];
    const float* beta  = (const float*)d_in[12];

    char* ws = (char*)d_ws;
    int*   batch_i = (int*)ws;                                  //  8 KB
    int*   mask_i  = (int*)(ws + 8192);                         // 16 KB
    float* k_ws    = (float*)(ws + 24576);                      //  8 MB
    float* v_ws    = (float*)(ws + 24576 + 8388608);            //  8 MB
    float* q_ws    = (float*)(ws + 24576 + 2*8388608);          //  4 MB
    float* gate_ws = (float*)(ws + 24576 + 2*8388608 + 4194304);
    float* feat_ws = (float*)(ws + 24576 + 2*8388608 + 2*4194304);

    float* out        = (float*)d_out;
    float* out_logits = out + (size_t)NND * IFZ;

    hipLaunchKernelGGL(detect_norm, dim3(1), dim3(256), 0, stream, mraw, braw, mask_i, batch_i);
    hipLaunchKernelGGL(kv_proj, dim3(2, 512), dim3(256), 0, stream, emb, Wk, Wv, k_ws, v_ws);
    hipLaunchKernelGGL(qg_proj, dim3(2, 256), dim3(256), 0, stream, x, Wq, Wg, bg, q_ws, gate_ws);
    hipLaunchKernelGGL(attn_kernel, dim3(NND), dim3(256), 0, stream,
                       k_ws, v_ws, q_ws, mask_i, batch_i, feat_ws, out_logits);
    hipLaunchKernelGGL(back_ln, dim3(NND), dim3(256), 0, stream,
                       gate_ws, feat_ws, x, Wback, bback, gamma, beta, out);
}

// Round 3
// 430.341 us; speedup vs baseline: 2.5615x; 2.5615x over previous
//
#include <hip/hip_runtime.h>
#include <hip/hip_bf16.h>

#define NND 2048
#define BBATCH 4
#define SS 1024
#define SFZ 384
#define IFZ 256
#define HH 8
#define AA 64
#define HA 512
#define NT 8      // nodes per attention block
#define SC 128    // s-chunk

// ---------------------------------------------------------------------------
// Kernel 0: detect storage dtype of mask/batch, normalize to int32, and
// compute per-batch node segments (batch is sorted).
// ---------------------------------------------------------------------------
__global__ void detect_norm(const void* __restrict__ mask_raw,
                            const void* __restrict__ batch_raw,
                            int* __restrict__ mask_i, int* __restrict__ batch_i,
                            int* __restrict__ seg)
{
    __shared__ int fl[4];
    __shared__ int fb;
    __shared__ int cnt[4];
    const int t = threadIdx.x;
    if (t < 4) { fl[t] = 0; cnt[t] = 0; }
    if (t == 0) fb = 0;
    __syncthreads();
    const unsigned char*  mb = (const unsigned char*)mask_raw;
    const unsigned short* mh = (const unsigned short*)mask_raw;
    const unsigned int*   mw = (const unsigned int*)mask_raw;
    int f0 = 0, f1 = 0, f2 = 0, f3 = 0;
    for (int i = t; i < 2048; i += 256) {
        unsigned short h = mh[i];
        if (h == 0x3f80u) f0 = 1;
        if ((i & 1) == 0 && h != 0) f1 = 1;
    }
    for (int i = t; i < 4096; i += 256)
        if ((i & 3) != 0 && mb[i] != 0) f2 = 1;
    for (int i = t; i < 1024; i += 256)
        if ((i & 1) != 0 && mw[i] != 0) f3 = 1;
    const int* bw = (const int*)batch_raw;
    int f4 = 0;
    for (int i = t + 1; i < 2048; i += 256)
        if (bw[i] < bw[i-1]) f4 = 1;
    if (f0) atomicOr(&fl[0], 1);
    if (f1) atomicOr(&fl[1], 1);
    if (f2) atomicOr(&fl[2], 1);
    if (f3) atomicOr(&fl[3], 1);
    if (f4) atomicOr(&fb, 1);
    __syncthreads();
    int mode;
    if (fl[0])      mode = fl[1] ? 1 : 0;
    else if (fl[2]) mode = 2;
    else if (fl[3]) mode = 3;
    else            mode = 4;
    for (int s = t; s < BBATCH*SS; s += 256) {
        int m;
        switch (mode) {
            case 0:  m = (mw[s]   != 0); break;
            case 1:  m = (mh[s]   != 0); break;
            case 2:  m = (mb[s]   != 0); break;
            case 3:  m = (mw[s]   != 0); break;
            default: m = (mw[2*s] != 0); break;
        }
        mask_i[s] = m;
    }
    const int b64 = fb;
    for (int i = t; i < NND; i += 256) {
        const int bv = (b64 ? bw[2*i] : bw[i]) & 3;
        batch_i[i] = bv;
        atomicAdd(&cnt[bv], 1);
    }
    __syncthreads();
    if (t == 0) {
        int s = 0;
        for (int b = 0; b < 4; ++b) { seg[2*b] = s; s += cnt[b]; seg[2*b+1] = s; }
    }
}

// ---------------------------------------------------------------------------
// Kernel 1: k = emb@Wk, v = emb@Wv  (16 rows/block, float4-blocked K-loop)
// ---------------------------------------------------------------------------
__global__ __launch_bounds__(256) void kv_proj(
    const float* __restrict__ emb,
    const float* __restrict__ Wk, const float* __restrict__ Wv,
    float* __restrict__ k_ws, float* __restrict__ v_ws)
{
    __shared__ float e_lds[16 * SFZ];   // 24 KB
    const int t   = threadIdx.x;
    const int r0  = blockIdx.y * 16;
    const int col = blockIdx.x * 256 + t;
    const float* ebase = emb + (size_t)r0 * SFZ;
    for (int i = t * 4; i < 16 * SFZ; i += 1024)
        *(float4*)&e_lds[i] = *(const float4*)&ebase[i];
    __syncthreads();
    float ak[16], av[16];
    #pragma unroll
    for (int r = 0; r < 16; ++r) { ak[r] = 0.f; av[r] = 0.f; }
    const float* pk = Wk + col;
    const float* pv = Wv + col;
    for (int kk = 0; kk < SFZ; kk += 4) {
        const float wk0 = pk[(size_t)(kk+0) * HA];
        const float wk1 = pk[(size_t)(kk+1) * HA];
        const float wk2 = pk[(size_t)(kk+2) * HA];
        const float wk3 = pk[(size_t)(kk+3) * HA];
        const float wv0 = pv[(size_t)(kk+0) * HA];
        const float wv1 = pv[(size_t)(kk+1) * HA];
        const float wv2 = pv[(size_t)(kk+2) * HA];
        const float wv3 = pv[(size_t)(kk+3) * HA];
        #pragma unroll
        for (int r = 0; r < 16; ++r) {
            const float4 e4 = *(const float4*)&e_lds[r * SFZ + kk];
            ak[r] = fmaf(e4.x, wk0, ak[r]); ak[r] = fmaf(e4.y, wk1, ak[r]);
            ak[r] = fmaf(e4.z, wk2, ak[r]); ak[r] = fmaf(e4.w, wk3, ak[r]);
            av[r] = fmaf(e4.x, wv0, av[r]); av[r] = fmaf(e4.y, wv1, av[r]);
            av[r] = fmaf(e4.z, wv2, av[r]); av[r] = fmaf(e4.w, wv3, av[r]);
        }
    }
    #pragma unroll
    for (int r = 0; r < 16; ++r) {
        k_ws[(size_t)(r0 + r) * HA + col] = ak[r];
        v_ws[(size_t)(r0 + r) * HA + col] = av[r];
    }
}

// ---------------------------------------------------------------------------
// Kernel 2: q = x@Wq, gate = sigmoid(x@Wg + bg)  (16 rows/block)
// ---------------------------------------------------------------------------
__global__ __launch_bounds__(256) void qg_proj(
    const float* __restrict__ x,
    const float* __restrict__ Wq, const float* __restrict__ Wg,
    const float* __restrict__ bg,
    float* __restrict__ q_ws, float* __restrict__ gate_ws)
{
    __shared__ float x_lds[16 * IFZ];   // 16 KB
    const int t   = threadIdx.x;
    const int r0  = blockIdx.y * 16;
    const int col = blockIdx.x * 256 + t;
    const float* xbase = x + (size_t)r0 * IFZ;
    for (int i = t * 4; i < 16 * IFZ; i += 1024)
        *(float4*)&x_lds[i] = *(const float4*)&xbase[i];
    __syncthreads();
    float aq[16], ag[16];
    #pragma unroll
    for (int r = 0; r < 16; ++r) { aq[r] = 0.f; ag[r] = 0.f; }
    const float* pq = Wq + col;
    const float* pg = Wg + col;
    for (int kk = 0; kk < IFZ; kk += 4) {
        const float wq0 = pq[(size_t)(kk+0) * HA];
        const float wq1 = pq[(size_t)(kk+1) * HA];
        const float wq2 = pq[(size_t)(kk+2) * HA];
        const float wq3 = pq[(size_t)(kk+3) * HA];
        const float wg0 = pg[(size_t)(kk+0) * HA];
        const float wg1 = pg[(size_t)(kk+1) * HA];
        const float wg2 = pg[(size_t)(kk+2) * HA];
        const float wg3 = pg[(size_t)(kk+3) * HA];
        #pragma unroll
        for (int r = 0; r < 16; ++r) {
            const float4 e4 = *(const float4*)&x_lds[r * IFZ + kk];
            aq[r] = fmaf(e4.x, wq0, aq[r]); aq[r] = fmaf(e4.y, wq1, aq[r]);
            aq[r] = fmaf(e4.z, wq2, aq[r]); aq[r] = fmaf(e4.w, wq3, aq[r]);
            ag[r] = fmaf(e4.x, wg0, ag[r]); ag[r] = fmaf(e4.y, wg1, ag[r]);
            ag[r] = fmaf(e4.z, wg2, ag[r]); ag[r] = fmaf(e4.w, wg3, ag[r]);
        }
    }
    const float bgv = bg[col];
    #pragma unroll
    for (int r = 0; r < 16; ++r) {
        q_ws[(size_t)(r0 + r) * HA + col]    = aq[r];
        const float z = ag[r] + bgv;
        gate_ws[(size_t)(r0 + r) * HA + col] = 1.f / (1.f + __expf(-z));
    }
}

// ---------------------------------------------------------------------------
// Kernel 3: flash-style attention, NT=8 nodes/block (single batch segment),
// s-chunks of 128 with online masked softmax. 3 phases per chunk.
// ---------------------------------------------------------------------------
__global__ __launch_bounds__(256) void attn_kernel(
    const float* __restrict__ k_ws, const float* __restrict__ v_ws,
    const float* __restrict__ q_ws, const int* __restrict__ mask_i,
    const int* __restrict__ seg, float* __restrict__ feat_ws,
    float* __restrict__ out_logits)
{
    __shared__ float q_l[NT][HH][68];     // 17.4 KB, pad 68: conflict-free b128
    __shared__ float sc_l[NT][HH][132];   // 33.8 KB, s-contiguous rows
    __shared__ float mch[SC];
    __shared__ float mst[NT*HH], lst[NT*HH], alp[NT*HH];
    const int t = threadIdx.x;
    const int b = blockIdx.y;
    const int n0 = seg[2*b] + blockIdx.x * NT;
    const int nend = seg[2*b + 1];
    if (n0 >= nend) return;
    const int nvalid = min(NT, nend - n0);

    for (int i = t; i < NT * HA; i += 256) {
        const int nn = i >> 9, rem = i & (HA - 1);
        q_l[nn][rem >> 6][rem & 63] = (nn < nvalid) ? q_ws[(size_t)(n0 + nn) * HA + rem] : 0.f;
    }
    if (t < NT*HH) { mst[t] = -3.0e38f; lst[t] = 0.f; }
    __syncthreads();

    const int h  = t & 7,  sl = t >> 3;   // score mapping: 8h x 32 s-groups
    const int fh = t >> 5, fl = t & 31;   // feat mapping:  8h x 32 a-lanes
    float facc[NT][2];
    #pragma unroll
    for (int n = 0; n < NT; ++n) { facc[n][0] = 0.f; facc[n][1] = 0.f; }

    const float* kbase = k_ws + (size_t)b * SS * HA;
    const float* vbase = v_ws + (size_t)b * SS * HA;

    for (int ch = 0; ch < SS / SC; ++ch) {
        const int s0 = ch * SC;
        if (t < SC) mch[t] = (float)mask_i[b * SS + s0 + t];
        // ---- scores: thread (h, sl) -> s = s0 + sl*4 + i, all NT nodes ----
        {
            float4 acc[NT];
            #pragma unroll
            for (int n = 0; n < NT; ++n) acc[n] = make_float4(0.f,0.f,0.f,0.f);
            const float* kp0 = kbase + (size_t)(s0 + sl * 4) * HA + h * AA;
            #pragma unroll 4
            for (int c = 0; c < 16; ++c) {
                const float4 k0 = *(const float4*)(kp0 + 0*HA + c*4);
                const float4 k1 = *(const float4*)(kp0 + 1*HA + c*4);
                const float4 k2 = *(const float4*)(kp0 + 2*HA + c*4);
                const float4 k3 = *(const float4*)(kp0 + 3*HA + c*4);
                #pragma unroll
                for (int n = 0; n < NT; ++n) {
                    const float4 qv = *(const float4*)&q_l[n][h][c*4];
                    acc[n].x = fmaf(k0.x,qv.x,acc[n].x); acc[n].x = fmaf(k0.y,qv.y,acc[n].x);
                    acc[n].x = fmaf(k0.z,qv.z,acc[n].x); acc[n].x = fmaf(k0.w,qv.w,acc[n].x);
                    acc[n].y = fmaf(k1.x,qv.x,acc[n].y); acc[n].y = fmaf(k1.y,qv.y,acc[n].y);
                    acc[n].y = fmaf(k1.z,qv.z,acc[n].y); acc[n].y = fmaf(k1.w,qv.w,acc[n].y);
                    acc[n].z = fmaf(k2.x,qv.x,acc[n].z); acc[n].z = fmaf(k2.y,qv.y,acc[n].z);
                    acc[n].z = fmaf(k2.z,qv.z,acc[n].z); acc[n].z = fmaf(k2.w,qv.w,acc[n].z);
                    acc[n].w = fmaf(k3.x,qv.x,acc[n].w); acc[n].w = fmaf(k3.y,qv.y,acc[n].w);
                    acc[n].w = fmaf(k3.z,qv.z,acc[n].w); acc[n].w = fmaf(k3.w,qv.w,acc[n].w);
                }
            }
            #pragma unroll
            for (int n = 0; n < NT; ++n) {
                float4 r;
                r.x = acc[n].x * 0.125f; r.y = acc[n].y * 0.125f;
                r.z = acc[n].z * 0.125f; r.w = acc[n].w * 0.125f;
                *(float4*)&sc_l[n][h][sl * 4] = r;
            }
        }
        __syncthreads();
        // ---- raw-score logits (pre-mask), heads 0+1 ----
        {
            const int ln = t >> 5, sl4 = (t & 31) * 4;
            const float4 a0 = *(const float4*)&sc_l[ln][0][sl4];
            const float4 a1 = *(const float4*)&sc_l[ln][1][sl4];
            if (ln < nvalid) {
                float4 o;
                o.x = a0.x + a1.x; o.y = a0.y + a1.y;
                o.z = a0.z + a1.z; o.w = a0.w + a1.w;
                *(float4*)&out_logits[(size_t)(n0 + ln) * SS + s0 + sl4] = o;
            }
        }
        // ---- online masked softmax: pair p=(n,h) over 4 lanes ----
        {
            const int p = t >> 2, j = t & 3;
            const int pn = p >> 3, ph = p & 7;
            float cm = -3.0e38f;
            #pragma unroll
            for (int ii = 0; ii < 8; ++ii) {
                const int s = j * 4 + ii * 16;
                const float4 v4 = *(const float4*)&sc_l[pn][ph][s];
                const float4 m4 = *(const float4*)&mch[s];
                cm = fmaxf(cm, (m4.x > 0.5f) ? v4.x : -3.0e38f);
                cm = fmaxf(cm, (m4.y > 0.5f) ? v4.y : -3.0e38f);
                cm = fmaxf(cm, (m4.z > 0.5f) ? v4.z : -3.0e38f);
                cm = fmaxf(cm, (m4.w > 0.5f) ? v4.w : -3.0e38f);
            }
            cm = fmaxf(cm, __shfl_xor(cm, 1));
            cm = fmaxf(cm, __shfl_xor(cm, 2));
            const float mold = mst[p];
            const float mnew = fmaxf(mold, cm);
            const float al   = __expf(mold - mnew);
            float csum = 0.f;
            #pragma unroll
            for (int ii = 0; ii < 8; ++ii) {
                const int s = j * 4 + ii * 16;
                const float4 v4 = *(const float4*)&sc_l[pn][ph][s];
                const float4 m4 = *(const float4*)&mch[s];
                float4 e;
                e.x = (m4.x > 0.5f) ? __expf(v4.x - mnew) : 0.f;
                e.y = (m4.y > 0.5f) ? __expf(v4.y - mnew) : 0.f;
                e.z = (m4.z > 0.5f) ? __expf(v4.z - mnew) : 0.f;
                e.w = (m4.w > 0.5f) ? __expf(v4.w - mnew) : 0.f;
                *(float4*)&sc_l[pn][ph][s] = e;
                csum += e.x + e.y + e.z + e.w;
            }
            csum += __shfl_xor(csum, 1);
            csum += __shfl_xor(csum, 2);
            if (j == 0) {
                mst[p] = mnew;
                lst[p] = lst[p] * al + csum;
                alp[p] = al;
            }
        }
        __syncthreads();
        // ---- feat accumulation: thread (fh, fl) -> a0 = fl*2 ----
        {
            #pragma unroll
            for (int n = 0; n < NT; ++n) {
                const float a = alp[n * 8 + fh];
                facc[n][0] *= a; facc[n][1] *= a;
            }
            const float* vp = vbase + (size_t)s0 * HA + fh * AA + fl * 2;
            #pragma unroll 2
            for (int sb = 0; sb < SC / 4; ++sb) {
                const float2 v0 = *(const float2*)(vp + (size_t)(sb*4 + 0) * HA);
                const float2 v1 = *(const float2*)(vp + (size_t)(sb*4 + 1) * HA);
                const float2 v2 = *(const float2*)(vp + (size_t)(sb*4 + 2) * HA);
                const float2 v3 = *(const float2*)(vp + (size_t)(sb*4 + 3) * HA);
                #pragma unroll
                for (int n = 0; n < NT; ++n) {
                    const float4 w = *(const float4*)&sc_l[n][fh][sb * 4];
                    facc[n][0] = fmaf(w.x, v0.x, facc[n][0]);
                    facc[n][0] = fmaf(w.y, v1.x, facc[n][0]);
                    facc[n][0] = fmaf(w.z, v2.x, facc[n][0]);
                    facc[n][0] = fmaf(w.w, v3.x, facc[n][0]);
                    facc[n][1] = fmaf(w.x, v0.y, facc[n][1]);
                    facc[n][1] = fmaf(w.y, v1.y, facc[n][1]);
                    facc[n][1] = fmaf(w.z, v2.y, facc[n][1]);
                    facc[n][1] = fmaf(w.w, v3.y, facc[n][1]);
                }
            }
        }
        __syncthreads();
    }
    // ---- epilogue: normalize, store feat ----
    #pragma unroll
    for (int n = 0; n < NT; ++n) {
        if (n < nvalid) {
            const float inv = 1.f / (lst[n * 8 + fh] + 1e-9f);
            float2 o;
            o.x = facc[n][0] * inv; o.y = facc[n][1] * inv;
            *(float2*)&feat_ws[(size_t)(n0 + n) * HA + fh * AA + fl * 2] = o;
        }
    }
}

// ---------------------------------------------------------------------------
// Kernel 4: 8 nodes/block: new = (gate*feat)@Wback + bback; residual; LN.
// ---------------------------------------------------------------------------
__global__ __launch_bounds__(256) void back_ln(
    const float* __restrict__ gate_ws, const float* __restrict__ feat_ws,
    const float* __restrict__ x,
    const float* __restrict__ Wback, const float* __restrict__ bback,
    const float* __restrict__ gamma, const float* __restrict__ beta,
    float* __restrict__ out)
{
    __shared__ float gf[8 * HA];   // 16 KB
    __shared__ float red1[8][4], red2[8][4];
    const int t = threadIdx.x, n0 = blockIdx.x * 8;
    for (int i = t; i < 8 * HA; i += 256)
        gf[i] = gate_ws[(size_t)n0 * HA + i] * feat_ws[(size_t)n0 * HA + i];
    __syncthreads();
    float acc[8];
    const float bb = bback[t];
    #pragma unroll
    for (int n = 0; n < 8; ++n) acc[n] = bb;
    const float* wb = Wback + t;
    for (int jj = 0; jj < HA; jj += 4) {
        const float w0 = wb[(size_t)(jj+0) * IFZ];
        const float w1 = wb[(size_t)(jj+1) * IFZ];
        const float w2 = wb[(size_t)(jj+2) * IFZ];
        const float w3 = wb[(size_t)(jj+3) * IFZ];
        #pragma unroll
        for (int n = 0; n < 8; ++n) {
            const float4 g4 = *(const float4*)&gf[n * HA + jj];
            acc[n] = fmaf(g4.x, w0, acc[n]); acc[n] = fmaf(g4.y, w1, acc[n]);
            acc[n] = fmaf(g4.z, w2, acc[n]); acc[n] = fmaf(g4.w, w3, acc[n]);
        }
    }
    float y[8];
    #pragma unroll
    for (int n = 0; n < 8; ++n)
        y[n] = fmaf(1.41421356237309515f, x[(size_t)(n0 + n) * IFZ + t], acc[n]);
    const int wid = t >> 6;
    #pragma unroll
    for (int n = 0; n < 8; ++n) {
        float s1 = y[n], s2 = y[n] * y[n];
        #pragma unroll
        for (int off = 32; off >= 1; off >>= 1) {
            s1 += __shfl_xor(s1, off);
            s2 += __shfl_xor(s2, off);
        }
        if ((t & 63) == 0) { red1[n][wid] = s1; red2[n][wid] = s2; }
    }
    __syncthreads();
    const float gm = gamma[t], bt = beta[t];
    #pragma unroll
    for (int n = 0; n < 8; ++n) {
        const float S1 = red1[n][0] + red1[n][1] + red1[n][2] + red1[n][3];
        const float S2 = red2[n][0] + red2[n][1] + red2[n][2] + red2[n][3];
        const float mu  = S1 * (1.f / IFZ);
        const float var = S2 * (1.f / IFZ) - mu * mu;
        const float r   = rsqrtf(var + 1e-5f);
        out[(size_t)(n0 + n) * IFZ + t] = (y[n] - mu) * r * gm + bt;
    }
}

extern "C" void kernel_launch(void* const* d_in, const int* in_sizes, int n_in,
                              void* d_out, int out_size, void* d_ws, size_t ws_size,
                              hipStream_t stream) {
    const float* x     = (const float*)d_in[0];
    const float* emb   = (const float*)d_in[1];
    const void*  mraw  = d_in[2];
    const void*  braw  = d_in[3];
    const float* Wq    = (const float*)d_in[4];
    const float* Wk    = (const float*)d_in[5];
    const float* Wv    = (const float*)d_in[6];
    const float* Wg    = (const float*)d_in[7];
    const float* bg    = (const float*)d_in[8];
    const float* Wback = (const float*)d_in[9];
    const float* bback = (const float*)d_in[10];
    const float* gamma = (const float*)d_in[11];
    const float* beta  = (const float*)d_in[12];

    char* ws = (char*)d_ws;
    int*   batch_i = (int*)ws;                                  //  8 KB
    int*   mask_i  = (int*)(ws + 8192);                         // 16 KB
    int*   seg     = (int*)(ws + 24576);                        // 32 B
    float* k_ws    = (float*)(ws + 32768);                      //  8 MB
    float* v_ws    = (float*)(ws + 32768 + 8388608);            //  8 MB
    float* q_ws    = (float*)(ws + 32768 + 2*8388608);          //  4 MB
    float* gate_ws = (float*)(ws + 32768 + 2*8388608 + 4194304);
    float* feat_ws = (float*)(ws + 32768 + 2*8388608 + 2*4194304);

    float* out        = (float*)d_out;
    float* out_logits = out + (size_t)NND * IFZ;

    hipLaunchKernelGGL(detect_norm, dim3(1), dim3(256), 0, stream, mraw, braw, mask_i, batch_i, seg);
    hipLaunchKernelGGL(kv_proj, dim3(2, 256), dim3(256), 0, stream, emb, Wk, Wv, k_ws, v_ws);
    hipLaunchKernelGGL(qg_proj, dim3(2, 128), dim3(256), 0, stream, x, Wq, Wg, bg, q_ws, gate_ws);
    hipLaunchKernelGGL(attn_kernel, dim3(256, 4), dim3(256), 0, stream,
                       k_ws, v_ws, q_ws, mask_i, seg, feat_ws, out_logits);
    hipLaunchKernelGGL(back_ln, dim3(256), dim3(256), 0, stream,
                       gate_ws, feat_ws, x, Wback, bback, gamma, beta, out);
}

// Round 4
// 359.217 us; speedup vs baseline: 3.0686x; 1.1980x over previous
//
#include <hip/hip_runtime.h>
#include <hip/hip_bf16.h>

#define NND 2048
#define BBATCH 4
#define SS 1024
#define SFZ 384
#define IFZ 256
#define HH 8
#define AA 64
#define HA 512
#define NT 16     // nodes per attention block (MFMA M)
#define SC 128    // s-chunk

typedef __attribute__((ext_vector_type(8))) short bf16x8;
typedef __attribute__((ext_vector_type(4))) float f32x4;

__device__ __forceinline__ unsigned short f2bf(float f) {
    union { float f; unsigned u; } a; a.f = f;
    unsigned r = a.u + 0x7fffu + ((a.u >> 16) & 1u);
    return (unsigned short)(r >> 16);
}

// ---------------------------------------------------------------------------
// Kernel 0: detect storage dtype of mask/batch; mask -> float 0/1; batch -> seg
// ---------------------------------------------------------------------------
__global__ void detect_norm(const void* __restrict__ mask_raw,
                            const void* __restrict__ batch_raw,
                            float* __restrict__ mask_f, int* __restrict__ seg)
{
    __shared__ int fl[4];
    __shared__ int fb;
    __shared__ int cnt[4];
    const int t = threadIdx.x;
    if (t < 4) { fl[t] = 0; cnt[t] = 0; }
    if (t == 0) fb = 0;
    __syncthreads();
    const unsigned char*  mb = (const unsigned char*)mask_raw;
    const unsigned short* mh = (const unsigned short*)mask_raw;
    const unsigned int*   mw = (const unsigned int*)mask_raw;
    int f0 = 0, f1 = 0, f2 = 0, f3 = 0;
    for (int i = t; i < 2048; i += 256) {
        unsigned short h = mh[i];
        if (h == 0x3f80u) f0 = 1;
        if ((i & 1) == 0 && h != 0) f1 = 1;
    }
    for (int i = t; i < 4096; i += 256)
        if ((i & 3) != 0 && mb[i] != 0) f2 = 1;
    for (int i = t; i < 1024; i += 256)
        if ((i & 1) != 0 && mw[i] != 0) f3 = 1;
    const int* bw = (const int*)batch_raw;
    int f4 = 0;
    for (int i = t + 1; i < 2048; i += 256)
        if (bw[i] < bw[i-1]) f4 = 1;
    if (f0) atomicOr(&fl[0], 1);
    if (f1) atomicOr(&fl[1], 1);
    if (f2) atomicOr(&fl[2], 1);
    if (f3) atomicOr(&fl[3], 1);
    if (f4) atomicOr(&fb, 1);
    __syncthreads();
    int mode;
    if (fl[0])      mode = fl[1] ? 1 : 0;
    else if (fl[2]) mode = 2;
    else if (fl[3]) mode = 3;
    else            mode = 4;
    for (int s = t; s < BBATCH*SS; s += 256) {
        int m;
        switch (mode) {
            case 0:  m = (mw[s]   != 0); break;
            case 1:  m = (mh[s]   != 0); break;
            case 2:  m = (mb[s]   != 0); break;
            case 3:  m = (mw[s]   != 0); break;
            default: m = (mw[2*s] != 0); break;
        }
        mask_f[s] = m ? 1.0f : 0.0f;
    }
    const int b64 = fb;
    for (int i = t; i < NND; i += 256) {
        const int bv = (b64 ? bw[2*i] : bw[i]) & 3;
        atomicAdd(&cnt[bv], 1);
    }
    __syncthreads();
    if (t == 0) {
        int s = 0;
        for (int b = 0; b < 4; ++b) { seg[2*b] = s; s += cnt[b]; seg[2*b+1] = s; }
    }
}

// ---------------------------------------------------------------------------
// Kernel 1: k = emb@Wk -> bf16 [B*S][HA]; v = emb@Wv -> bf16 TRANSPOSED [B][HA][S]
// ---------------------------------------------------------------------------
__global__ __launch_bounds__(256) void kv_proj(
    const float* __restrict__ emb,
    const float* __restrict__ Wk, const float* __restrict__ Wv,
    unsigned short* __restrict__ k_bf, unsigned short* __restrict__ vT_bf)
{
    __shared__ float e_lds[16 * SFZ];   // 24 KB
    const int t   = threadIdx.x;
    const int r0  = blockIdx.y * 16;    // global row (b*S + s), block stays in one b
    const int col = blockIdx.x * 256 + t;
    const float* ebase = emb + (size_t)r0 * SFZ;
    for (int i = t * 4; i < 16 * SFZ; i += 1024)
        *(float4*)&e_lds[i] = *(const float4*)&ebase[i];
    __syncthreads();
    float ak[16], av[16];
    #pragma unroll
    for (int r = 0; r < 16; ++r) { ak[r] = 0.f; av[r] = 0.f; }
    const float* pk = Wk + col;
    const float* pv = Wv + col;
    for (int kk = 0; kk < SFZ; kk += 4) {
        const float wk0 = pk[(size_t)(kk+0) * HA];
        const float wk1 = pk[(size_t)(kk+1) * HA];
        const float wk2 = pk[(size_t)(kk+2) * HA];
        const float wk3 = pk[(size_t)(kk+3) * HA];
        const float wv0 = pv[(size_t)(kk+0) * HA];
        const float wv1 = pv[(size_t)(kk+1) * HA];
        const float wv2 = pv[(size_t)(kk+2) * HA];
        const float wv3 = pv[(size_t)(kk+3) * HA];
        #pragma unroll
        for (int r = 0; r < 16; ++r) {
            const float4 e4 = *(const float4*)&e_lds[r * SFZ + kk];
            ak[r] = fmaf(e4.x, wk0, ak[r]); ak[r] = fmaf(e4.y, wk1, ak[r]);
            ak[r] = fmaf(e4.z, wk2, ak[r]); ak[r] = fmaf(e4.w, wk3, ak[r]);
            av[r] = fmaf(e4.x, wv0, av[r]); av[r] = fmaf(e4.y, wv1, av[r]);
            av[r] = fmaf(e4.z, wv2, av[r]); av[r] = fmaf(e4.w, wv3, av[r]);
        }
    }
    #pragma unroll
    for (int r = 0; r < 16; ++r)
        k_bf[(size_t)(r0 + r) * HA + col] = f2bf(ak[r]);
    // vT[b][col][s]: 16 consecutive s -> 32B aligned vector store
    const int b = r0 >> 10, s = r0 & (SS - 1);
    unsigned tv[8];
    #pragma unroll
    for (int i = 0; i < 8; ++i)
        tv[i] = (unsigned)f2bf(av[2*i]) | ((unsigned)f2bf(av[2*i+1]) << 16);
    unsigned short* vrow = vT_bf + ((size_t)b * HA + col) * SS + s;
    *(uint4*)(vrow)     = make_uint4(tv[0], tv[1], tv[2], tv[3]);
    *(uint4*)(vrow + 8) = make_uint4(tv[4], tv[5], tv[6], tv[7]);
}

// ---------------------------------------------------------------------------
// Kernel 2: q = x@Wq -> bf16; gate = sigmoid(x@Wg + bg) -> fp32
// ---------------------------------------------------------------------------
__global__ __launch_bounds__(256) void qg_proj(
    const float* __restrict__ x,
    const float* __restrict__ Wq, const float* __restrict__ Wg,
    const float* __restrict__ bg,
    unsigned short* __restrict__ q_bf, float* __restrict__ gate_ws)
{
    __shared__ float x_lds[16 * IFZ];   // 16 KB
    const int t   = threadIdx.x;
    const int r0  = blockIdx.y * 16;
    const int col = blockIdx.x * 256 + t;
    const float* xbase = x + (size_t)r0 * IFZ;
    for (int i = t * 4; i < 16 * IFZ; i += 1024)
        *(float4*)&x_lds[i] = *(const float4*)&xbase[i];
    __syncthreads();
    float aq[16], ag[16];
    #pragma unroll
    for (int r = 0; r < 16; ++r) { aq[r] = 0.f; ag[r] = 0.f; }
    const float* pq = Wq + col;
    const float* pg = Wg + col;
    for (int kk = 0; kk < IFZ; kk += 4) {
        const float wq0 = pq[(size_t)(kk+0) * HA];
        const float wq1 = pq[(size_t)(kk+1) * HA];
        const float wq2 = pq[(size_t)(kk+2) * HA];
        const float wq3 = pq[(size_t)(kk+3) * HA];
        const float wg0 = pg[(size_t)(kk+0) * HA];
        const float wg1 = pg[(size_t)(kk+1) * HA];
        const float wg2 = pg[(size_t)(kk+2) * HA];
        const float wg3 = pg[(size_t)(kk+3) * HA];
        #pragma unroll
        for (int r = 0; r < 16; ++r) {
            const float4 e4 = *(const float4*)&x_lds[r * IFZ + kk];
            aq[r] = fmaf(e4.x, wq0, aq[r]); aq[r] = fmaf(e4.y, wq1, aq[r]);
            aq[r] = fmaf(e4.z, wq2, aq[r]); aq[r] = fmaf(e4.w, wq3, aq[r]);
            ag[r] = fmaf(e4.x, wg0, ag[r]); ag[r] = fmaf(e4.y, wg1, ag[r]);
            ag[r] = fmaf(e4.z, wg2, ag[r]); ag[r] = fmaf(e4.w, wg3, ag[r]);
        }
    }
    const float bgv = bg[col];
    #pragma unroll
    for (int r = 0; r < 16; ++r) {
        q_bf[(size_t)(r0 + r) * HA + col] = f2bf(aq[r]);
        const float z = ag[r] + bgv;
        gate_ws[(size_t)(r0 + r) * HA + col] = 1.f / (1.f + __expf(-z));
    }
}

// ---------------------------------------------------------------------------
// Kernel 3: MFMA flash attention. 16 nodes/block, wave = one head,
// blockIdx.z selects heads 0-3 / 4-7. Per 128-s chunk: QK^T (MFMA, B-frags
// straight from global k_bf), raw-score logits (h0+h1), per-wave online
// masked softmax in LDS, PV (MFMA, A-frag from LDS scores, B-frag from vT).
// ---------------------------------------------------------------------------
__global__ __launch_bounds__(256) void attn_kernel(
    const unsigned short* __restrict__ k_bf, const unsigned short* __restrict__ vT_bf,
    const unsigned short* __restrict__ q_bf, const float* __restrict__ mask_f,
    const int* __restrict__ seg, float* __restrict__ feat_ws,
    float* __restrict__ out_logits)
{
    __shared__ float sc[4 * NT * 132];      // 33.8 KB: per-wave [16 nodes][128+4]
    __shared__ float mch[4][SC];            // per-wave mask copy (no cross-wave hazard)
    __shared__ float mst[64], lst[64], alp[64];
    const int t = threadIdx.x;
    const int b = blockIdx.y;
    const int n0 = seg[2*b] + blockIdx.x * NT;
    const int nend = seg[2*b + 1];
    if (n0 >= nend) return;
    const int nvalid = min(NT, nend - n0);

    const int w    = t >> 6;
    const int lane = t & 63;
    const int m16  = lane & 15;
    const int quad = lane >> 4;
    const int h    = blockIdx.z * 4 + w;

    if (lane < 16) { mst[w*16 + lane] = -3.0e38f; lst[w*16 + lane] = 0.f; }

    // loop-invariant A-frags: q[node][h*64 + ka + quad*8 .. +7]
    int nq = n0 + m16; if (nq >= nend) nq = nend - 1;
    const unsigned short* qp = q_bf + (size_t)nq * HA + h * AA + quad * 8;
    const bf16x8 qa0 = *(const bf16x8*)qp;
    const bf16x8 qa1 = *(const bf16x8*)(qp + 32);

    const unsigned short* kb = k_bf + (size_t)b * SS * HA + h * AA;
    const unsigned short* vb = vT_bf + ((size_t)b * HA + h * AA) * SS;
    float* scw = &sc[w * NT * 132];

    f32x4 facc[4];
    #pragma unroll
    for (int a = 0; a < 4; ++a) facc[a] = (f32x4){0.f, 0.f, 0.f, 0.f};

    for (int ch = 0; ch < SS / SC; ++ch) {
        const int s0 = ch * SC;
        mch[w][lane]      = mask_f[b * SS + s0 + lane];
        mch[w][lane + 64] = mask_f[b * SS + s0 + lane + 64];
        // ---- phase A: scores for 8 s-tiles of 16 ----
        #pragma unroll
        for (int st = 0; st < 8; ++st) {
            const unsigned short* kp = kb + (size_t)(s0 + st*16 + m16) * HA + quad * 8;
            const bf16x8 b0 = *(const bf16x8*)kp;
            const bf16x8 b1 = *(const bf16x8*)(kp + 32);
            f32x4 d = (f32x4){0.f, 0.f, 0.f, 0.f};
            d = __builtin_amdgcn_mfma_f32_16x16x32_bf16(qa0, b0, d, 0, 0, 0);
            d = __builtin_amdgcn_mfma_f32_16x16x32_bf16(qa1, b1, d, 0, 0, 0);
            #pragma unroll
            for (int r = 0; r < 4; ++r)
                scw[(quad*4 + r) * 132 + st*16 + m16] = d[r] * 0.125f;
        }
        __syncthreads();
        // ---- logits (raw pre-mask scores, heads 0+1; z==0 blocks only) ----
        if (blockIdx.z == 0) {
            for (int i = t; i < NT * SC; i += 256) {
                const int nn = i >> 7, sp = i & 127;
                if (nn < nvalid)
                    out_logits[(size_t)(n0 + nn) * SS + s0 + sp] =
                        sc[nn * 132 + sp] + sc[NT*132 + nn * 132 + sp];
            }
        }
        __syncthreads();
        // ---- phase B: per-wave online masked softmax ----
        {
            const int nd = lane >> 2, qt = lane & 3;
            float* row = &scw[nd * 132 + qt * 32];
            const float* mrow = &mch[w][qt * 32];
            float cm = -3.0e38f;
            #pragma unroll
            for (int i2 = 0; i2 < 8; ++i2) {
                const float4 v4 = *(const float4*)&row[i2 * 4];
                const float4 m4 = *(const float4*)&mrow[i2 * 4];
                cm = fmaxf(cm, (m4.x > 0.5f) ? v4.x : -3.0e38f);
                cm = fmaxf(cm, (m4.y > 0.5f) ? v4.y : -3.0e38f);
                cm = fmaxf(cm, (m4.z > 0.5f) ? v4.z : -3.0e38f);
                cm = fmaxf(cm, (m4.w > 0.5f) ? v4.w : -3.0e38f);
            }
            cm = fmaxf(cm, __shfl_xor(cm, 1));
            cm = fmaxf(cm, __shfl_xor(cm, 2));
            const float mold = mst[w*16 + nd];
            const float mnew = fmaxf(mold, cm);
            const float al   = __expf(mold - mnew);
            float csum = 0.f;
            #pragma unroll
            for (int i2 = 0; i2 < 8; ++i2) {
                const float4 v4 = *(const float4*)&row[i2 * 4];
                const float4 m4 = *(const float4*)&mrow[i2 * 4];
                float4 e;
                e.x = (m4.x > 0.5f) ? __expf(v4.x - mnew) : 0.f;
                e.y = (m4.y > 0.5f) ? __expf(v4.y - mnew) : 0.f;
                e.z = (m4.z > 0.5f) ? __expf(v4.z - mnew) : 0.f;
                e.w = (m4.w > 0.5f) ? __expf(v4.w - mnew) : 0.f;
                *(float4*)&row[i2 * 4] = e;
                csum += e.x + e.y + e.z + e.w;
            }
            csum += __shfl_xor(csum, 1);
            csum += __shfl_xor(csum, 2);
            if (qt == 0) {
                mst[w*16 + nd] = mnew;
                lst[w*16 + nd] = lst[w*16 + nd] * al + csum;
                alp[w*16 + nd] = al;
            }
        }
        // ---- phase C: PV accumulate (rescale by alpha first) ----
        {
            float alR[4];
            #pragma unroll
            for (int r = 0; r < 4; ++r) alR[r] = alp[w*16 + quad*4 + r];
            #pragma unroll
            for (int a = 0; a < 4; ++a)
                #pragma unroll
                for (int r = 0; r < 4; ++r) facc[a][r] *= alR[r];
            #pragma unroll
            for (int sub = 0; sub < 4; ++sub) {
                const float* spnp = &scw[m16 * 132 + sub * 32 + quad * 8];
                const float4 p0 = *(const float4*)spnp;
                const float4 p1 = *(const float4*)(spnp + 4);
                bf16x8 pa;
                pa[0] = (short)f2bf(p0.x); pa[1] = (short)f2bf(p0.y);
                pa[2] = (short)f2bf(p0.z); pa[3] = (short)f2bf(p0.w);
                pa[4] = (short)f2bf(p1.x); pa[5] = (short)f2bf(p1.y);
                pa[6] = (short)f2bf(p1.z); pa[7] = (short)f2bf(p1.w);
                const unsigned short* vp0 = vb + (size_t)m16 * SS + s0 + sub * 32 + quad * 8;
                #pragma unroll
                for (int a = 0; a < 4; ++a) {
                    const bf16x8 vfr = *(const bf16x8*)(vp0 + (size_t)(a * 16) * SS);
                    facc[a] = __builtin_amdgcn_mfma_f32_16x16x32_bf16(pa, vfr, facc[a], 0, 0, 0);
                }
            }
        }
        __syncthreads();   // protect scw/mch for next chunk's cross-phase uses
    }
    // ---- epilogue: normalize by l, write feat ----
    float linv[4];
    #pragma unroll
    for (int r = 0; r < 4; ++r) linv[r] = 1.f / (lst[w*16 + quad*4 + r] + 1e-9f);
    #pragma unroll
    for (int a = 0; a < 4; ++a)
        #pragma unroll
        for (int r = 0; r < 4; ++r) {
            const int nn = quad*4 + r;
            if (nn < nvalid)
                feat_ws[(size_t)(n0 + nn) * HA + h * AA + a * 16 + m16] = facc[a][r] * linv[r];
        }
}

// ---------------------------------------------------------------------------
// Kernel 4: 8 nodes/block: new = (gate*feat)@Wback + bback; residual; LN.
// ---------------------------------------------------------------------------
__global__ __launch_bounds__(256) void back_ln(
    const float* __restrict__ gate_ws, const float* __restrict__ feat_ws,
    const float* __restrict__ x,
    const float* __restrict__ Wback, const float* __restrict__ bback,
    const float* __restrict__ gamma, const float* __restrict__ beta,
    float* __restrict__ out)
{
    __shared__ float gf[8 * HA];   // 16 KB
    __shared__ float red1[8][4], red2[8][4];
    const int t = threadIdx.x, n0 = blockIdx.x * 8;
    for (int i = t; i < 8 * HA; i += 256)
        gf[i] = gate_ws[(size_t)n0 * HA + i] * feat_ws[(size_t)n0 * HA + i];
    __syncthreads();
    float acc[8];
    const float bb = bback[t];
    #pragma unroll
    for (int n = 0; n < 8; ++n) acc[n] = bb;
    const float* wb = Wback + t;
    for (int jj = 0; jj < HA; jj += 4) {
        const float w0 = wb[(size_t)(jj+0) * IFZ];
        const float w1 = wb[(size_t)(jj+1) * IFZ];
        const float w2 = wb[(size_t)(jj+2) * IFZ];
        const float w3 = wb[(size_t)(jj+3) * IFZ];
        #pragma unroll
        for (int n = 0; n < 8; ++n) {
            const float4 g4 = *(const float4*)&gf[n * HA + jj];
            acc[n] = fmaf(g4.x, w0, acc[n]); acc[n] = fmaf(g4.y, w1, acc[n]);
            acc[n] = fmaf(g4.z, w2, acc[n]); acc[n] = fmaf(g4.w, w3, acc[n]);
        }
    }
    float y[8];
    #pragma unroll
    for (int n = 0; n < 8; ++n)
        y[n] = fmaf(1.41421356237309515f, x[(size_t)(n0 + n) * IFZ + t], acc[n]);
    const int wid = t >> 6;
    #pragma unroll
    for (int n = 0; n < 8; ++n) {
        float s1 = y[n], s2 = y[n] * y[n];
        #pragma unroll
        for (int off = 32; off >= 1; off >>= 1) {
            s1 += __shfl_xor(s1, off);
            s2 += __shfl_xor(s2, off);
        }
        if ((t & 63) == 0) { red1[n][wid] = s1; red2[n][wid] = s2; }
    }
    __syncthreads();
    const float gm = gamma[t], bt = beta[t];
    #pragma unroll
    for (int n = 0; n < 8; ++n) {
        const float S1 = red1[n][0] + red1[n][1] + red1[n][2] + red1[n][3];
        const float S2 = red2[n][0] + red2[n][1] + red2[n][2] + red2[n][3];
        const float mu  = S1 * (1.f / IFZ);
        const float var = S2 * (1.f / IFZ) - mu * mu;
        const float r   = rsqrtf(var + 1e-5f);
        out[(size_t)(n0 + n) * IFZ + t] = (y[n] - mu) * r * gm + bt;
    }
}

extern "C" void kernel_launch(void* const* d_in, const int* in_sizes, int n_in,
                              void* d_out, int out_size, void* d_ws, size_t ws_size,
                              hipStream_t stream) {
    const float* x     = (const float*)d_in[0];
    const float* emb   = (const float*)d_in[1];
    const void*  mraw  = d_in[2];
    const void*  braw  = d_in[3];
    const float* Wq    = (const float*)d_in[4];
    const float* Wk    = (const float*)d_in[5];
    const float* Wv    = (const float*)d_in[6];
    const float* Wg    = (const float*)d_in[7];
    const float* bg    = (const float*)d_in[8];
    const float* Wback = (const float*)d_in[9];
    const float* bback = (const float*)d_in[10];
    const float* gamma = (const float*)d_in[11];
    const float* beta  = (const float*)d_in[12];

    char* ws = (char*)d_ws;
    float*          mask_f  = (float*)ws;                              // 16 KB
    int*            seg     = (int*)(ws + 16384);                      // 64 B
    unsigned short* k_bf    = (unsigned short*)(ws + 32768);           // 4 MB
    unsigned short* vT_bf   = (unsigned short*)(ws + 32768 + 4194304); // 4 MB
    unsigned short* q_bf    = (unsigned short*)(ws + 32768 + 2*4194304); // 2 MB
    float*          gate_ws = (float*)(ws + 32768 + 2*4194304 + 2097152); // 4 MB
    float*          feat_ws = (float*)(ws + 32768 + 3*4194304 + 2097152); // 4 MB

    float* out        = (float*)d_out;
    float* out_logits = out + (size_t)NND * IFZ;

    hipLaunchKernelGGL(detect_norm, dim3(1), dim3(256), 0, stream, mraw, braw, mask_f, seg);
    hipLaunchKernelGGL(kv_proj, dim3(2, 256), dim3(256), 0, stream, emb, Wk, Wv, k_bf, vT_bf);
    hipLaunchKernelGGL(qg_proj, dim3(2, 128), dim3(256), 0, stream, x, Wq, Wg, bg, q_bf, gate_ws);
    hipLaunchKernelGGL(attn_kernel, dim3(NND / NT, 4, 2), dim3(256), 0, stream,
                       k_bf, vT_bf, q_bf, mask_f, seg, feat_ws, out_logits);
    hipLaunchKernelGGL(back_ln, dim3(NND / 8), dim3(256), 0, stream,
                       gate_ws, feat_ws, x, Wback, bback, gamma, beta, out);
}

// Round 5
// 309.834 us; speedup vs baseline: 3.5578x; 1.1594x over previous
//
#include <hip/hip_runtime.h>
#include <hip/hip_bf16.h>

#define NND 2048
#define BBATCH 4
#define SS 1024
#define SFZ 384
#define IFZ 256
#define HH 8
#define AA 64
#define HA 512
#define NT 16     // nodes per attention block (MFMA M)
#define SC 128    // s-chunk

typedef __attribute__((ext_vector_type(8))) short bf16x8;
typedef __attribute__((ext_vector_type(4))) float f32x4;

__device__ __forceinline__ unsigned short f2bf(float f) {
    union { float f; unsigned u; } a; a.f = f;
    unsigned r = a.u + 0x7fffu + ((a.u >> 16) & 1u);
    return (unsigned short)(r >> 16);
}

// ---------------------------------------------------------------------------
// Kernel 0: detect storage dtype of mask/batch; mask -> float 0/1; batch -> seg
// ---------------------------------------------------------------------------
__global__ void detect_norm(const void* __restrict__ mask_raw,
                            const void* __restrict__ batch_raw,
                            float* __restrict__ mask_f, int* __restrict__ seg)
{
    __shared__ int fl[4];
    __shared__ int fb;
    __shared__ int cnt[4];
    const int t = threadIdx.x;
    if (t < 4) { fl[t] = 0; cnt[t] = 0; }
    if (t == 0) fb = 0;
    __syncthreads();
    const unsigned char*  mb = (const unsigned char*)mask_raw;
    const unsigned short* mh = (const unsigned short*)mask_raw;
    const unsigned int*   mw = (const unsigned int*)mask_raw;
    int f0 = 0, f1 = 0, f2 = 0, f3 = 0;
    for (int i = t; i < 2048; i += 256) {
        unsigned short h = mh[i];
        if (h == 0x3f80u) f0 = 1;
        if ((i & 1) == 0 && h != 0) f1 = 1;
    }
    for (int i = t; i < 4096; i += 256)
        if ((i & 3) != 0 && mb[i] != 0) f2 = 1;
    for (int i = t; i < 1024; i += 256)
        if ((i & 1) != 0 && mw[i] != 0) f3 = 1;
    const int* bw = (const int*)batch_raw;
    int f4 = 0;
    for (int i = t + 1; i < 2048; i += 256)
        if (bw[i] < bw[i-1]) f4 = 1;
    if (f0) atomicOr(&fl[0], 1);
    if (f1) atomicOr(&fl[1], 1);
    if (f2) atomicOr(&fl[2], 1);
    if (f3) atomicOr(&fl[3], 1);
    if (f4) atomicOr(&fb, 1);
    __syncthreads();
    int mode;
    if (fl[0])      mode = fl[1] ? 1 : 0;
    else if (fl[2]) mode = 2;
    else if (fl[3]) mode = 3;
    else            mode = 4;
    for (int s = t; s < BBATCH*SS; s += 256) {
        int m;
        switch (mode) {
            case 0:  m = (mw[s]   != 0); break;
            case 1:  m = (mh[s]   != 0); break;
            case 2:  m = (mb[s]   != 0); break;
            case 3:  m = (mw[s]   != 0); break;
            default: m = (mw[2*s] != 0); break;
        }
        mask_f[s] = m ? 1.0f : 0.0f;
    }
    const int b64 = fb;
    for (int i = t; i < NND; i += 256) {
        const int bv = (b64 ? bw[2*i] : bw[i]) & 3;
        atomicAdd(&cnt[bv], 1);
    }
    __syncthreads();
    if (t == 0) {
        int s = 0;
        for (int b = 0; b < 4; ++b) { seg[2*b] = s; s += cnt[b]; seg[2*b+1] = s; }
    }
}

// ---------------------------------------------------------------------------
// Kernel 1: k = emb@Wk -> bf16 [row][col]; v = emb@Wv -> bf16 [row][col]
// (coalesced stores; vT built by transpose kernel)
// ---------------------------------------------------------------------------
__global__ __launch_bounds__(256) void kv_proj(
    const float* __restrict__ emb,
    const float* __restrict__ Wk, const float* __restrict__ Wv,
    unsigned short* __restrict__ k_bf, unsigned short* __restrict__ v_bf)
{
    __shared__ float e_lds[16 * SFZ];   // 24 KB
    const int t   = threadIdx.x;
    const int r0  = blockIdx.y * 16;
    const int col = blockIdx.x * 256 + t;
    const float* ebase = emb + (size_t)r0 * SFZ;
    for (int i = t * 4; i < 16 * SFZ; i += 1024)
        *(float4*)&e_lds[i] = *(const float4*)&ebase[i];
    __syncthreads();
    float ak[16], av[16];
    #pragma unroll
    for (int r = 0; r < 16; ++r) { ak[r] = 0.f; av[r] = 0.f; }
    const float* pk = Wk + col;
    const float* pv = Wv + col;
    for (int kk = 0; kk < SFZ; kk += 4) {
        const float wk0 = pk[(size_t)(kk+0) * HA];
        const float wk1 = pk[(size_t)(kk+1) * HA];
        const float wk2 = pk[(size_t)(kk+2) * HA];
        const float wk3 = pk[(size_t)(kk+3) * HA];
        const float wv0 = pv[(size_t)(kk+0) * HA];
        const float wv1 = pv[(size_t)(kk+1) * HA];
        const float wv2 = pv[(size_t)(kk+2) * HA];
        const float wv3 = pv[(size_t)(kk+3) * HA];
        #pragma unroll
        for (int r = 0; r < 16; ++r) {
            const float4 e4 = *(const float4*)&e_lds[r * SFZ + kk];
            ak[r] = fmaf(e4.x, wk0, ak[r]); ak[r] = fmaf(e4.y, wk1, ak[r]);
            ak[r] = fmaf(e4.z, wk2, ak[r]); ak[r] = fmaf(e4.w, wk3, ak[r]);
            av[r] = fmaf(e4.x, wv0, av[r]); av[r] = fmaf(e4.y, wv1, av[r]);
            av[r] = fmaf(e4.z, wv2, av[r]); av[r] = fmaf(e4.w, wv3, av[r]);
        }
    }
    #pragma unroll
    for (int r = 0; r < 16; ++r) {
        k_bf[(size_t)(r0 + r) * HA + col] = f2bf(ak[r]);
        v_bf[(size_t)(r0 + r) * HA + col] = f2bf(av[r]);
    }
}

// ---------------------------------------------------------------------------
// Kernel 1b: vT[b][col][s] = v[b*S+s][col], 64x64 LDS tiles, coalesced both ways
// ---------------------------------------------------------------------------
__global__ __launch_bounds__(256) void transpose_v(
    const unsigned short* __restrict__ v_bf, unsigned short* __restrict__ vT_bf)
{
    __shared__ unsigned short tile[64][65];
    const int t = threadIdx.x;
    const int s0 = blockIdx.x * 64, c0 = blockIdx.y * 64, b = blockIdx.z;
    const int tr = t >> 6, tc = t & 63;
    #pragma unroll
    for (int r = 0; r < 16; ++r)
        tile[tr + r*4][tc] = v_bf[(size_t)(b * SS + s0 + tr + r*4) * HA + c0 + tc];
    __syncthreads();
    #pragma unroll
    for (int r = 0; r < 16; ++r)
        vT_bf[((size_t)b * HA + c0 + tr + r*4) * SS + s0 + tc] = tile[tc][tr + r*4];
}

// ---------------------------------------------------------------------------
// Kernel 2: q = x@Wq -> bf16; gate = sigmoid(x@Wg + bg) -> fp32
// ---------------------------------------------------------------------------
__global__ __launch_bounds__(256) void qg_proj(
    const float* __restrict__ x,
    const float* __restrict__ Wq, const float* __restrict__ Wg,
    const float* __restrict__ bg,
    unsigned short* __restrict__ q_bf, float* __restrict__ gate_ws)
{
    __shared__ float x_lds[16 * IFZ];   // 16 KB
    const int t   = threadIdx.x;
    const int r0  = blockIdx.y * 16;
    const int col = blockIdx.x * 256 + t;
    const float* xbase = x + (size_t)r0 * IFZ;
    for (int i = t * 4; i < 16 * IFZ; i += 1024)
        *(float4*)&x_lds[i] = *(const float4*)&xbase[i];
    __syncthreads();
    float aq[16], ag[16];
    #pragma unroll
    for (int r = 0; r < 16; ++r) { aq[r] = 0.f; ag[r] = 0.f; }
    const float* pq = Wq + col;
    const float* pg = Wg + col;
    for (int kk = 0; kk < IFZ; kk += 4) {
        const float wq0 = pq[(size_t)(kk+0) * HA];
        const float wq1 = pq[(size_t)(kk+1) * HA];
        const float wq2 = pq[(size_t)(kk+2) * HA];
        const float wq3 = pq[(size_t)(kk+3) * HA];
        const float wg0 = pg[(size_t)(kk+0) * HA];
        const float wg1 = pg[(size_t)(kk+1) * HA];
        const float wg2 = pg[(size_t)(kk+2) * HA];
        const float wg3 = pg[(size_t)(kk+3) * HA];
        #pragma unroll
        for (int r = 0; r < 16; ++r) {
            const float4 e4 = *(const float4*)&x_lds[r * IFZ + kk];
            aq[r] = fmaf(e4.x, wq0, aq[r]); aq[r] = fmaf(e4.y, wq1, aq[r]);
            aq[r] = fmaf(e4.z, wq2, aq[r]); aq[r] = fmaf(e4.w, wq3, aq[r]);
            ag[r] = fmaf(e4.x, wg0, ag[r]); ag[r] = fmaf(e4.y, wg1, ag[r]);
            ag[r] = fmaf(e4.z, wg2, ag[r]); ag[r] = fmaf(e4.w, wg3, ag[r]);
        }
    }
    const float bgv = bg[col];
    #pragma unroll
    for (int r = 0; r < 16; ++r) {
        q_bf[(size_t)(r0 + r) * HA + col] = f2bf(aq[r]);
        const float z = ag[r] + bgv;
        gate_ws[(size_t)(r0 + r) * HA + col] = 1.f / (1.f + __expf(-z));
    }
}

// ---------------------------------------------------------------------------
// Kernel 3a: raw-score logits = (q[:, :128] . k[:, :128]) / 8  (heads 0+1).
// MFMA GEMM, 16 nodes x 256 s per block (wave = 64 s).
// ---------------------------------------------------------------------------
__global__ __launch_bounds__(256) void logits_kernel(
    const unsigned short* __restrict__ k_bf, const unsigned short* __restrict__ q_bf,
    const int* __restrict__ seg, float* __restrict__ out_logits)
{
    const int t = threadIdx.x;
    const int b = blockIdx.y;
    const int n0 = seg[2*b] + blockIdx.x * 16;
    const int nend = seg[2*b + 1];
    if (n0 >= nend) return;
    const int nvalid = min(16, nend - n0);
    const int w = t >> 6, lane = t & 63, m16 = lane & 15, quad = lane >> 4;
    int nq = n0 + m16; if (nq >= nend) nq = nend - 1;
    const unsigned short* qp = q_bf + (size_t)nq * HA + quad * 8;
    bf16x8 qa[4];
    #pragma unroll
    for (int kb2 = 0; kb2 < 4; ++kb2) qa[kb2] = *(const bf16x8*)(qp + kb2 * 32);
    const int s_base = blockIdx.z * 256 + w * 64;
    #pragma unroll
    for (int st = 0; st < 4; ++st) {
        const int s = s_base + st * 16 + m16;
        const unsigned short* kp = k_bf + (size_t)(b * SS + s) * HA + quad * 8;
        f32x4 d = (f32x4){0.f, 0.f, 0.f, 0.f};
        #pragma unroll
        for (int kb2 = 0; kb2 < 4; ++kb2)
            d = __builtin_amdgcn_mfma_f32_16x16x32_bf16(qa[kb2], *(const bf16x8*)(kp + kb2 * 32), d, 0, 0, 0);
        #pragma unroll
        for (int r = 0; r < 4; ++r) {
            const int row = quad * 4 + r;
            if (row < nvalid)
                out_logits[(size_t)(n0 + row) * SS + s_base + st * 16 + m16] = d[r] * 0.125f;
        }
    }
}

// ---------------------------------------------------------------------------
// Kernel 3b: barrier-free MFMA flash attention. Wave = (16 nodes x 1 head),
// z = (head-half, S-split). Wave-private LDS; intra-wave DS ordering only.
// ---------------------------------------------------------------------------
__global__ __launch_bounds__(256) void attn_kernel(
    const unsigned short* __restrict__ k_bf, const unsigned short* __restrict__ vT_bf,
    const unsigned short* __restrict__ q_bf, const float* __restrict__ mask_f,
    const int* __restrict__ seg, float* __restrict__ part_O, float2* __restrict__ part_ml)
{
    __shared__ float sc[4 * NT * 132];      // 33.8 KB, wave-private slices
    __shared__ float mst[64], lst[64], alp[64];
    const int t = threadIdx.x;
    const int b = blockIdx.y;
    const int hz    = blockIdx.z >> 1;
    const int split = blockIdx.z & 1;
    const int n0 = seg[2*b] + blockIdx.x * NT;
    const int nend = seg[2*b + 1];
    if (n0 >= nend) return;
    const int nvalid = min(NT, nend - n0);

    const int w = t >> 6, lane = t & 63;
    const int m16 = lane & 15, quad = lane >> 4;
    const int h = hz * 4 + w;

    if (quad == 0) { mst[w*16 + m16] = -3.0e38f; lst[w*16 + m16] = 0.f; }

    int nq = n0 + m16; if (nq >= nend) nq = nend - 1;
    const unsigned short* qp = q_bf + (size_t)nq * HA + h * AA + quad * 8;
    const bf16x8 qa0 = *(const bf16x8*)qp;
    const bf16x8 qa1 = *(const bf16x8*)(qp + 32);

    const unsigned short* kb = k_bf + (size_t)b * SS * HA + h * AA;
    const unsigned short* vb = vT_bf + ((size_t)b * HA + h * AA) * SS;
    float* scw = &sc[w * NT * 132];

    f32x4 facc[4];
    #pragma unroll
    for (int a = 0; a < 4; ++a) facc[a] = (f32x4){0.f, 0.f, 0.f, 0.f};

    for (int ch = 0; ch < 4; ++ch) {
        const int s0 = split * 512 + ch * SC;
        // ---- phase A: QK^T scores -> wave-private LDS ----
        #pragma unroll
        for (int st = 0; st < 8; ++st) {
            const unsigned short* kp = kb + (size_t)(s0 + st*16 + m16) * HA + quad * 8;
            const bf16x8 b0 = *(const bf16x8*)kp;
            const bf16x8 b1 = *(const bf16x8*)(kp + 32);
            f32x4 d = (f32x4){0.f, 0.f, 0.f, 0.f};
            d = __builtin_amdgcn_mfma_f32_16x16x32_bf16(qa0, b0, d, 0, 0, 0);
            d = __builtin_amdgcn_mfma_f32_16x16x32_bf16(qa1, b1, d, 0, 0, 0);
            #pragma unroll
            for (int r = 0; r < 4; ++r)
                scw[(quad*4 + r) * 132 + st*16 + m16] = d[r] * 0.125f;
        }
        asm volatile("" ::: "memory");
        // ---- phase B: online masked softmax, row = m16, 4 lanes (quad) per row
        //      element mapping quad*4 + i2*16 -> uniform bank groups ----
        {
            const float* mrow = mask_f + b * SS + s0;
            float* row = &scw[m16 * 132];
            float4 sv[8], mk[8];
            #pragma unroll
            for (int i2 = 0; i2 < 8; ++i2) {
                sv[i2] = *(const float4*)&row[quad*4 + i2*16];
                mk[i2] = *(const float4*)(mrow + quad*4 + i2*16);
            }
            float cm = -3.0e38f;
            #pragma unroll
            for (int i2 = 0; i2 < 8; ++i2) {
                cm = fmaxf(cm, (mk[i2].x > 0.5f) ? sv[i2].x : -3.0e38f);
                cm = fmaxf(cm, (mk[i2].y > 0.5f) ? sv[i2].y : -3.0e38f);
                cm = fmaxf(cm, (mk[i2].z > 0.5f) ? sv[i2].z : -3.0e38f);
                cm = fmaxf(cm, (mk[i2].w > 0.5f) ? sv[i2].w : -3.0e38f);
            }
            cm = fmaxf(cm, __shfl_xor(cm, 16));
            cm = fmaxf(cm, __shfl_xor(cm, 32));
            const float mold = mst[w*16 + m16];
            const float mnew = fmaxf(mold, cm);
            const float al   = __expf(mold - mnew);
            float csum = 0.f;
            #pragma unroll
            for (int i2 = 0; i2 < 8; ++i2) {
                float4 e;
                e.x = (mk[i2].x > 0.5f) ? __expf(sv[i2].x - mnew) : 0.f;
                e.y = (mk[i2].y > 0.5f) ? __expf(sv[i2].y - mnew) : 0.f;
                e.z = (mk[i2].z > 0.5f) ? __expf(sv[i2].z - mnew) : 0.f;
                e.w = (mk[i2].w > 0.5f) ? __expf(sv[i2].w - mnew) : 0.f;
                *(float4*)&row[quad*4 + i2*16] = e;
                csum += e.x + e.y + e.z + e.w;
            }
            csum += __shfl_xor(csum, 16);
            csum += __shfl_xor(csum, 32);
            if (quad == 0) {
                mst[w*16 + m16] = mnew;
                lst[w*16 + m16] = lst[w*16 + m16] * al + csum;
                alp[w*16 + m16] = al;
            }
        }
        asm volatile("" ::: "memory");
        // ---- phase C: PV accumulate ----
        {
            float alR[4];
            #pragma unroll
            for (int r = 0; r < 4; ++r) alR[r] = alp[w*16 + quad*4 + r];
            #pragma unroll
            for (int a = 0; a < 4; ++a)
                #pragma unroll
                for (int r = 0; r < 4; ++r) facc[a][r] *= alR[r];
            #pragma unroll
            for (int sub = 0; sub < 4; ++sub) {
                const float* spnp = &scw[m16 * 132 + sub * 32 + quad * 8];
                const float4 p0 = *(const float4*)spnp;
                const float4 p1 = *(const float4*)(spnp + 4);
                bf16x8 pa;
                pa[0] = (short)f2bf(p0.x); pa[1] = (short)f2bf(p0.y);
                pa[2] = (short)f2bf(p0.z); pa[3] = (short)f2bf(p0.w);
                pa[4] = (short)f2bf(p1.x); pa[5] = (short)f2bf(p1.y);
                pa[6] = (short)f2bf(p1.z); pa[7] = (short)f2bf(p1.w);
                const unsigned short* vp0 = vb + (size_t)m16 * SS + s0 + sub * 32 + quad * 8;
                #pragma unroll
                for (int a = 0; a < 4; ++a) {
                    const bf16x8 vfr = *(const bf16x8*)(vp0 + (size_t)(a * 16) * SS);
                    facc[a] = __builtin_amdgcn_mfma_f32_16x16x32_bf16(pa, vfr, facc[a], 0, 0, 0);
                }
            }
        }
        asm volatile("" ::: "memory");
    }
    // ---- epilogue: write unnormalized partial O and (m,l) ----
    float* po = part_O + (size_t)split * NND * HA;
    #pragma unroll
    for (int a = 0; a < 4; ++a)
        #pragma unroll
        for (int r = 0; r < 4; ++r) {
            const int row = quad*4 + r;
            if (row < nvalid)
                po[(size_t)(n0 + row) * HA + h * AA + a * 16 + m16] = facc[a][r];
        }
    if (quad == 0 && m16 < nvalid)
        part_ml[(size_t)split * NND * HH + (size_t)(n0 + m16) * HH + h] =
            make_float2(mst[w*16 + m16], lst[w*16 + m16]);
}

// ---------------------------------------------------------------------------
// Kernel 3c: combine the 2 S-split partials -> feat
// ---------------------------------------------------------------------------
__global__ __launch_bounds__(256) void combine_kernel(
    const float* __restrict__ part_O, const float2* __restrict__ part_ml,
    float* __restrict__ feat_ws)
{
    const size_t i = (size_t)blockIdx.x * 256 + threadIdx.x;
    const int n = (int)(i >> 9);
    const int c = (int)(i & (HA - 1));
    const int h = c >> 6;
    const float2 ml0 = part_ml[(size_t)n * HH + h];
    const float2 ml1 = part_ml[(size_t)NND * HH + (size_t)n * HH + h];
    const float m  = fmaxf(ml0.x, ml1.x);
    const float w0 = __expf(ml0.x - m);
    const float w1 = __expf(ml1.x - m);
    const float l  = ml0.y * w0 + ml1.y * w1;
    const float O  = part_O[i] * w0 + part_O[(size_t)NND * HA + i] * w1;
    feat_ws[i] = O / (l + 1e-9f);
}

// ---------------------------------------------------------------------------
// Kernel 4: 8 nodes/block: new = (gate*feat)@Wback + bback; residual; LN.
// ---------------------------------------------------------------------------
__global__ __launch_bounds__(256) void back_ln(
    const float* __restrict__ gate_ws, const float* __restrict__ feat_ws,
    const float* __restrict__ x,
    const float* __restrict__ Wback, const float* __restrict__ bback,
    const float* __restrict__ gamma, const float* __restrict__ beta,
    float* __restrict__ out)
{
    __shared__ float gf[8 * HA];   // 16 KB
    __shared__ float red1[8][4], red2[8][4];
    const int t = threadIdx.x, n0 = blockIdx.x * 8;
    for (int i = t; i < 8 * HA; i += 256)
        gf[i] = gate_ws[(size_t)n0 * HA + i] * feat_ws[(size_t)n0 * HA + i];
    __syncthreads();
    float acc[8];
    const float bb = bback[t];
    #pragma unroll
    for (int n = 0; n < 8; ++n) acc[n] = bb;
    const float* wb = Wback + t;
    for (int jj = 0; jj < HA; jj += 4) {
        const float w0 = wb[(size_t)(jj+0) * IFZ];
        const float w1 = wb[(size_t)(jj+1) * IFZ];
        const float w2 = wb[(size_t)(jj+2) * IFZ];
        const float w3 = wb[(size_t)(jj+3) * IFZ];
        #pragma unroll
        for (int n = 0; n < 8; ++n) {
            const float4 g4 = *(const float4*)&gf[n * HA + jj];
            acc[n] = fmaf(g4.x, w0, acc[n]); acc[n] = fmaf(g4.y, w1, acc[n]);
            acc[n] = fmaf(g4.z, w2, acc[n]); acc[n] = fmaf(g4.w, w3, acc[n]);
        }
    }
    float y[8];
    #pragma unroll
    for (int n = 0; n < 8; ++n)
        y[n] = fmaf(1.41421356237309515f, x[(size_t)(n0 + n) * IFZ + t], acc[n]);
    const int wid = t >> 6;
    #pragma unroll
    for (int n = 0; n < 8; ++n) {
        float s1 = y[n], s2 = y[n] * y[n];
        #pragma unroll
        for (int off = 32; off >= 1; off >>= 1) {
            s1 += __shfl_xor(s1, off);
            s2 += __shfl_xor(s2, off);
        }
        if ((t & 63) == 0) { red1[n][wid] = s1; red2[n][wid] = s2; }
    }
    __syncthreads();
    const float gm = gamma[t], bt = beta[t];
    #pragma unroll
    for (int n = 0; n < 8; ++n) {
        const float S1 = red1[n][0] + red1[n][1] + red1[n][2] + red1[n][3];
        const float S2 = red2[n][0] + red2[n][1] + red2[n][2] + red2[n][3];
        const float mu  = S1 * (1.f / IFZ);
        const float var = S2 * (1.f / IFZ) - mu * mu;
        const float r   = rsqrtf(var + 1e-5f);
        out[(size_t)(n0 + n) * IFZ + t] = (y[n] - mu) * r * gm + bt;
    }
}

extern "C" void kernel_launch(void* const* d_in, const int* in_sizes, int n_in,
                              void* d_out, int out_size, void* d_ws, size_t ws_size,
                              hipStream_t stream) {
    const float* x     = (const float*)d_in[0];
    const float* emb   = (const float*)d_in[1];
    const void*  mraw  = d_in[2];
    const void*  braw  = d_in[3];
    const float* Wq    = (const float*)d_in[4];
    const float* Wk    = (const float*)d_in[5];
    const float* Wv    = (const float*)d_in[6];
    const float* Wg    = (const float*)d_in[7];
    const float* bg    = (const float*)d_in[8];
    const float* Wback = (const float*)d_in[9];
    const float* bback = (const float*)d_in[10];
    const float* gamma = (const float*)d_in[11];
    const float* beta  = (const float*)d_in[12];

    char* ws = (char*)d_ws;
    const size_t MB = 1048576;
    float*          mask_f  = (float*)ws;                               // 16 KB
    int*            seg     = (int*)(ws + 16384);                       // 64 B
    unsigned short* k_bf    = (unsigned short*)(ws + 32768);            // 4 MB
    unsigned short* v_bf    = (unsigned short*)(ws + 32768 + 4*MB);     // 4 MB
    unsigned short* vT_bf   = (unsigned short*)(ws + 32768 + 8*MB);     // 4 MB
    unsigned short* q_bf    = (unsigned short*)(ws + 32768 + 12*MB);    // 2 MB
    float*          gate_ws = (float*)(ws + 32768 + 14*MB);             // 4 MB
    float*          feat_ws = (float*)(ws + 32768 + 18*MB);             // 4 MB
    float*          part_O  = (float*)(ws + 32768 + 22*MB);             // 8 MB
    float2*         part_ml = (float2*)(ws + 32768 + 30*MB);            // 256 KB

    float* out        = (float*)d_out;
    float* out_logits = out + (size_t)NND * IFZ;

    hipLaunchKernelGGL(detect_norm, dim3(1), dim3(256), 0, stream, mraw, braw, mask_f, seg);
    hipLaunchKernelGGL(kv_proj, dim3(2, 256), dim3(256), 0, stream, emb, Wk, Wv, k_bf, v_bf);
    hipLaunchKernelGGL(transpose_v, dim3(16, 8, 4), dim3(256), 0, stream, v_bf, vT_bf);
    hipLaunchKernelGGL(qg_proj, dim3(2, 128), dim3(256), 0, stream, x, Wq, Wg, bg, q_bf, gate_ws);
    hipLaunchKernelGGL(logits_kernel, dim3(128, 4, 4), dim3(256), 0, stream,
                       k_bf, q_bf, seg, out_logits);
    hipLaunchKernelGGL(attn_kernel, dim3(128, 4, 4), dim3(256), 0, stream,
                       k_bf, vT_bf, q_bf, mask_f, seg, part_O, part_ml);
    hipLaunchKernelGGL(combine_kernel, dim3((NND * HA) / 256), dim3(256), 0, stream,
                       part_O, part_ml, feat_ws);
    hipLaunchKernelGGL(back_ln, dim3(NND / 8), dim3(256), 0, stream,
                       gate_ws, feat_ws, x, Wback, bback, gamma, beta, out);
}

// Round 6
// 249.317 us; speedup vs baseline: 4.4213x; 1.2427x over previous
//
#include <hip/hip_runtime.h>
#include <hip/hip_bf16.h>

#define NND 2048
#define BBATCH 4
#define SS 1024
#define SFZ 384
#define IFZ 256
#define HH 8
#define AA 64
#define HA 512
#define NT 16
#define SC 128

typedef __attribute__((ext_vector_type(8))) short bf16x8;
typedef __attribute__((ext_vector_type(4))) float f32x4;

__device__ __forceinline__ unsigned short f2bf(float f) {
    union { float f; unsigned u; } a; a.f = f;
    unsigned r = a.u + 0x7fffu + ((a.u >> 16) & 1u);
    return (unsigned short)(r >> 16);
}

// ---------------------------------------------------------------------------
// Kernel 0: detect storage dtype of mask/batch; mask -> float 0/1; batch -> seg
// ---------------------------------------------------------------------------
__global__ void detect_norm(const void* __restrict__ mask_raw,
                            const void* __restrict__ batch_raw,
                            float* __restrict__ mask_f, int* __restrict__ seg)
{
    __shared__ int fl[4];
    __shared__ int fb;
    __shared__ int cnt[4];
    const int t = threadIdx.x;
    if (t < 4) { fl[t] = 0; cnt[t] = 0; }
    if (t == 0) fb = 0;
    __syncthreads();
    const unsigned char*  mb = (const unsigned char*)mask_raw;
    const unsigned short* mh = (const unsigned short*)mask_raw;
    const unsigned int*   mw = (const unsigned int*)mask_raw;
    int f0 = 0, f1 = 0, f2 = 0, f3 = 0;
    for (int i = t; i < 2048; i += 256) {
        unsigned short h = mh[i];
        if (h == 0x3f80u) f0 = 1;
        if ((i & 1) == 0 && h != 0) f1 = 1;
    }
    for (int i = t; i < 4096; i += 256)
        if ((i & 3) != 0 && mb[i] != 0) f2 = 1;
    for (int i = t; i < 1024; i += 256)
        if ((i & 1) != 0 && mw[i] != 0) f3 = 1;
    const int* bw = (const int*)batch_raw;
    int f4 = 0;
    for (int i = t + 1; i < 2048; i += 256)
        if (bw[i] < bw[i-1]) f4 = 1;
    if (f0) atomicOr(&fl[0], 1);
    if (f1) atomicOr(&fl[1], 1);
    if (f2) atomicOr(&fl[2], 1);
    if (f3) atomicOr(&fl[3], 1);
    if (f4) atomicOr(&fb, 1);
    __syncthreads();
    int mode;
    if (fl[0])      mode = fl[1] ? 1 : 0;
    else if (fl[2]) mode = 2;
    else if (fl[3]) mode = 3;
    else            mode = 4;
    for (int s = t; s < BBATCH*SS; s += 256) {
        int m;
        switch (mode) {
            case 0:  m = (mw[s]   != 0); break;
            case 1:  m = (mh[s]   != 0); break;
            case 2:  m = (mb[s]   != 0); break;
            case 3:  m = (mw[s]   != 0); break;
            default: m = (mw[2*s] != 0); break;
        }
        mask_f[s] = m ? 1.0f : 0.0f;
    }
    const int b64 = fb;
    for (int i = t; i < NND; i += 256) {
        const int bv = (b64 ? bw[2*i] : bw[i]) & 3;
        atomicAdd(&cnt[bv], 1);
    }
    __syncthreads();
    if (t == 0) {
        int s = 0;
        for (int b = 0; b < 4; ++b) { seg[2*b] = s; s += cnt[b]; seg[2*b+1] = s; }
    }
}

// ---------------------------------------------------------------------------
// Kernel P: prep — weights transpose-convert fp32->bf16 (W[K][N] -> WT[N][K]),
// and flat conversion of emb/x to bf16.
// blocks [0,48) WkT | [48,96) WvT | [96,128) WqT | [128,160) WgT |
// [160,192) WbackT | [192,576) emb | [576,704) x
// ---------------------------------------------------------------------------
__device__ __forceinline__ void tile_transpose(
    const float* __restrict__ src, unsigned short* __restrict__ dst,
    int K, int N, int kt, int nt, int t)
{
    __shared__ unsigned short tile[64][65];
    const int k0 = kt * 64, n0 = nt * 64;
    const int tr = t >> 6, tc = t & 63;
    #pragma unroll
    for (int r = 0; r < 16; ++r)
        tile[tr + r*4][tc] = f2bf(src[(size_t)(k0 + tr + r*4) * N + n0 + tc]);
    __syncthreads();
    #pragma unroll
    for (int r = 0; r < 16; ++r)
        dst[(size_t)(n0 + tr + r*4) * K + k0 + tc] = tile[tc][tr + r*4];
}

__global__ __launch_bounds__(256) void prep_kernel(
    const float* __restrict__ emb, const float* __restrict__ x,
    const float* __restrict__ Wk, const float* __restrict__ Wv,
    const float* __restrict__ Wq, const float* __restrict__ Wg,
    const float* __restrict__ Wback,
    unsigned short* __restrict__ emb_bf, unsigned short* __restrict__ x_bf,
    unsigned short* __restrict__ WkT, unsigned short* __restrict__ WvT,
    unsigned short* __restrict__ WqT, unsigned short* __restrict__ WgT,
    unsigned short* __restrict__ WbackT)
{
    const int bx = blockIdx.x, t = threadIdx.x;
    if (bx < 48)        { tile_transpose(Wk, WkT, SFZ, HA, bx/8, bx%8, t); return; }
    if (bx < 96)        { const int i = bx-48;  tile_transpose(Wv, WvT, SFZ, HA, i/8, i%8, t); return; }
    if (bx < 128)       { const int i = bx-96;  tile_transpose(Wq, WqT, IFZ, HA, i/8, i%8, t); return; }
    if (bx < 160)       { const int i = bx-128; tile_transpose(Wg, WgT, IFZ, HA, i/8, i%8, t); return; }
    if (bx < 192)       { const int i = bx-160; tile_transpose(Wback, WbackT, HA, IFZ, i/4, i%4, t); return; }
    const float* src; unsigned short* dst; size_t base;
    if (bx < 576) { src = emb; dst = emb_bf; base = (size_t)(bx - 192) * 4096; }
    else          { src = x;   dst = x_bf;   base = (size_t)(bx - 576) * 4096; }
    #pragma unroll
    for (int it = 0; it < 4; ++it) {
        const size_t idx = base + (size_t)(t + it * 256) * 4;
        const float4 f = *(const float4*)&src[idx];
        ushort4 o;
        o.x = f2bf(f.x); o.y = f2bf(f.y); o.z = f2bf(f.z); o.w = f2bf(f.w);
        *(ushort4*)&dst[idx] = o;
    }
}

// ---------------------------------------------------------------------------
// Kernel 1: MFMA k/v projection. C[4096x512] = emb_bf[4096x384] @ W^T.
// grid (256, 2): y=0 -> k, y=1 -> v. Wave w: rows r0..r0+16, cols [w*128,w*128+128)
// ---------------------------------------------------------------------------
__global__ __launch_bounds__(256) void kv_mfma(
    const unsigned short* __restrict__ emb_bf,
    const unsigned short* __restrict__ WkT, const unsigned short* __restrict__ WvT,
    unsigned short* __restrict__ k_bf, unsigned short* __restrict__ v_bf)
{
    const int t = threadIdx.x, w = t >> 6, lane = t & 63;
    const int m16 = lane & 15, quad = lane >> 4;
    const int r0 = blockIdx.x * 16;
    const unsigned short* Wt  = blockIdx.y ? WvT : WkT;
    unsigned short*       outp = blockIdx.y ? v_bf : k_bf;
    const unsigned short* ap = emb_bf + (size_t)(r0 + m16) * SFZ + quad * 8;
    bf16x8 af[12];
    #pragma unroll
    for (int j = 0; j < 12; ++j) af[j] = *(const bf16x8*)(ap + j * 32);
    #pragma unroll
    for (int nt = 0; nt < 8; ++nt) {
        const int n0 = w * 128 + nt * 16;
        const unsigned short* bp = Wt + (size_t)(n0 + m16) * SFZ + quad * 8;
        f32x4 d = (f32x4){0.f, 0.f, 0.f, 0.f};
        #pragma unroll
        for (int j = 0; j < 12; ++j)
            d = __builtin_amdgcn_mfma_f32_16x16x32_bf16(af[j], *(const bf16x8*)(bp + j * 32), d, 0, 0, 0);
        #pragma unroll
        for (int r = 0; r < 4; ++r)
            outp[(size_t)(r0 + quad * 4 + r) * HA + n0 + m16] = f2bf(d[r]);
    }
}

// ---------------------------------------------------------------------------
// Kernel 1b: vT[b][col][s] = v[b*S+s][col]
// ---------------------------------------------------------------------------
__global__ __launch_bounds__(256) void transpose_v(
    const unsigned short* __restrict__ v_bf, unsigned short* __restrict__ vT_bf)
{
    __shared__ unsigned short tile[64][65];
    const int t = threadIdx.x;
    const int s0 = blockIdx.x * 64, c0 = blockIdx.y * 64, b = blockIdx.z;
    const int tr = t >> 6, tc = t & 63;
    #pragma unroll
    for (int r = 0; r < 16; ++r)
        tile[tr + r*4][tc] = v_bf[(size_t)(b * SS + s0 + tr + r*4) * HA + c0 + tc];
    __syncthreads();
    #pragma unroll
    for (int r = 0; r < 16; ++r)
        vT_bf[((size_t)b * HA + c0 + tr + r*4) * SS + s0 + tc] = tile[tc][tr + r*4];
}

// ---------------------------------------------------------------------------
// Kernel 2: MFMA q/gate projection. grid (128, 4): tensor = y>>1 (0=q,1=gate),
// half = y&1 selects cols [half*256, half*256+256); wave covers 64 cols.
// ---------------------------------------------------------------------------
__global__ __launch_bounds__(256) void qg_mfma(
    const unsigned short* __restrict__ x_bf,
    const unsigned short* __restrict__ WqT, const unsigned short* __restrict__ WgT,
    const float* __restrict__ bg,
    unsigned short* __restrict__ q_bf, float* __restrict__ gate_ws)
{
    const int t = threadIdx.x, w = t >> 6, lane = t & 63;
    const int m16 = lane & 15, quad = lane >> 4;
    const int r0 = blockIdx.x * 16;
    const int tensor = blockIdx.y >> 1, half = blockIdx.y & 1;
    const unsigned short* Wt = tensor ? WgT : WqT;
    const unsigned short* ap = x_bf + (size_t)(r0 + m16) * IFZ + quad * 8;
    bf16x8 af[8];
    #pragma unroll
    for (int j = 0; j < 8; ++j) af[j] = *(const bf16x8*)(ap + j * 32);
    #pragma unroll
    for (int nt = 0; nt < 4; ++nt) {
        const int n0 = half * 256 + w * 64 + nt * 16;
        const unsigned short* bp = Wt + (size_t)(n0 + m16) * IFZ + quad * 8;
        f32x4 d = (f32x4){0.f, 0.f, 0.f, 0.f};
        #pragma unroll
        for (int j = 0; j < 8; ++j)
            d = __builtin_amdgcn_mfma_f32_16x16x32_bf16(af[j], *(const bf16x8*)(bp + j * 32), d, 0, 0, 0);
        if (tensor == 0) {
            #pragma unroll
            for (int r = 0; r < 4; ++r)
                q_bf[(size_t)(r0 + quad * 4 + r) * HA + n0 + m16] = f2bf(d[r]);
        } else {
            const float bgv = bg[n0 + m16];
            #pragma unroll
            for (int r = 0; r < 4; ++r)
                gate_ws[(size_t)(r0 + quad * 4 + r) * HA + n0 + m16] =
                    1.f / (1.f + __expf(-(d[r] + bgv)));
        }
    }
}

// ---------------------------------------------------------------------------
// Kernel 3a: raw-score logits = (q[:, :128] . k[:, :128]) / 8  (heads 0+1)
// ---------------------------------------------------------------------------
__global__ __launch_bounds__(256) void logits_kernel(
    const unsigned short* __restrict__ k_bf, const unsigned short* __restrict__ q_bf,
    const int* __restrict__ seg, float* __restrict__ out_logits)
{
    const int t = threadIdx.x;
    const int b = blockIdx.y;
    const int n0 = seg[2*b] + blockIdx.x * 16;
    const int nend = seg[2*b + 1];
    if (n0 >= nend) return;
    const int nvalid = min(16, nend - n0);
    const int w = t >> 6, lane = t & 63, m16 = lane & 15, quad = lane >> 4;
    int nq = n0 + m16; if (nq >= nend) nq = nend - 1;
    const unsigned short* qp = q_bf + (size_t)nq * HA + quad * 8;
    bf16x8 qa[4];
    #pragma unroll
    for (int kb2 = 0; kb2 < 4; ++kb2) qa[kb2] = *(const bf16x8*)(qp + kb2 * 32);
    const int s_base = blockIdx.z * 256 + w * 64;
    #pragma unroll
    for (int st = 0; st < 4; ++st) {
        const int s = s_base + st * 16 + m16;
        const unsigned short* kp = k_bf + (size_t)(b * SS + s) * HA + quad * 8;
        f32x4 d = (f32x4){0.f, 0.f, 0.f, 0.f};
        #pragma unroll
        for (int kb2 = 0; kb2 < 4; ++kb2)
            d = __builtin_amdgcn_mfma_f32_16x16x32_bf16(qa[kb2], *(const bf16x8*)(kp + kb2 * 32), d, 0, 0, 0);
        #pragma unroll
        for (int r = 0; r < 4; ++r) {
            const int row = quad * 4 + r;
            if (row < nvalid)
                out_logits[(size_t)(n0 + row) * SS + s_base + st * 16 + m16] = d[r] * 0.125f;
        }
    }
}

// ---------------------------------------------------------------------------
// Kernel 3b: barrier-free MFMA flash attention (wave = 16 nodes x 1 head)
// ---------------------------------------------------------------------------
__global__ __launch_bounds__(256) void attn_kernel(
    const unsigned short* __restrict__ k_bf, const unsigned short* __restrict__ vT_bf,
    const unsigned short* __restrict__ q_bf, const float* __restrict__ mask_f,
    const int* __restrict__ seg, float* __restrict__ part_O, float2* __restrict__ part_ml)
{
    __shared__ float sc[4 * NT * 132];
    __shared__ float mst[64], lst[64], alp[64];
    const int t = threadIdx.x;
    const int b = blockIdx.y;
    const int hz    = blockIdx.z >> 1;
    const int split = blockIdx.z & 1;
    const int n0 = seg[2*b] + blockIdx.x * NT;
    const int nend = seg[2*b + 1];
    if (n0 >= nend) return;
    const int nvalid = min(NT, nend - n0);

    const int w = t >> 6, lane = t & 63;
    const int m16 = lane & 15, quad = lane >> 4;
    const int h = hz * 4 + w;

    if (quad == 0) { mst[w*16 + m16] = -3.0e38f; lst[w*16 + m16] = 0.f; }

    int nq = n0 + m16; if (nq >= nend) nq = nend - 1;
    const unsigned short* qp = q_bf + (size_t)nq * HA + h * AA + quad * 8;
    const bf16x8 qa0 = *(const bf16x8*)qp;
    const bf16x8 qa1 = *(const bf16x8*)(qp + 32);

    const unsigned short* kb = k_bf + (size_t)b * SS * HA + h * AA;
    const unsigned short* vb = vT_bf + ((size_t)b * HA + h * AA) * SS;
    float* scw = &sc[w * NT * 132];

    f32x4 facc[4];
    #pragma unroll
    for (int a = 0; a < 4; ++a) facc[a] = (f32x4){0.f, 0.f, 0.f, 0.f};

    for (int ch = 0; ch < 4; ++ch) {
        const int s0 = split * 512 + ch * SC;
        #pragma unroll
        for (int st = 0; st < 8; ++st) {
            const unsigned short* kp = kb + (size_t)(s0 + st*16 + m16) * HA + quad * 8;
            const bf16x8 b0 = *(const bf16x8*)kp;
            const bf16x8 b1 = *(const bf16x8*)(kp + 32);
            f32x4 d = (f32x4){0.f, 0.f, 0.f, 0.f};
            d = __builtin_amdgcn_mfma_f32_16x16x32_bf16(qa0, b0, d, 0, 0, 0);
            d = __builtin_amdgcn_mfma_f32_16x16x32_bf16(qa1, b1, d, 0, 0, 0);
            #pragma unroll
            for (int r = 0; r < 4; ++r)
                scw[(quad*4 + r) * 132 + st*16 + m16] = d[r] * 0.125f;
        }
        asm volatile("" ::: "memory");
        {
            const float* mrow = mask_f + b * SS + s0;
            float* row = &scw[m16 * 132];
            float4 sv[8], mk[8];
            #pragma unroll
            for (int i2 = 0; i2 < 8; ++i2) {
                sv[i2] = *(const float4*)&row[quad*4 + i2*16];
                mk[i2] = *(const float4*)(mrow + quad*4 + i2*16);
            }
            float cm = -3.0e38f;
            #pragma unroll
            for (int i2 = 0; i2 < 8; ++i2) {
                cm = fmaxf(cm, (mk[i2].x > 0.5f) ? sv[i2].x : -3.0e38f);
                cm = fmaxf(cm, (mk[i2].y > 0.5f) ? sv[i2].y : -3.0e38f);
                cm = fmaxf(cm, (mk[i2].z > 0.5f) ? sv[i2].z : -3.0e38f);
                cm = fmaxf(cm, (mk[i2].w > 0.5f) ? sv[i2].w : -3.0e38f);
            }
            cm = fmaxf(cm, __shfl_xor(cm, 16));
            cm = fmaxf(cm, __shfl_xor(cm, 32));
            const float mold = mst[w*16 + m16];
            const float mnew = fmaxf(mold, cm);
            const float al   = __expf(mold - mnew);
            float csum = 0.f;
            #pragma unroll
            for (int i2 = 0; i2 < 8; ++i2) {
                float4 e;
                e.x = (mk[i2].x > 0.5f) ? __expf(sv[i2].x - mnew) : 0.f;
                e.y = (mk[i2].y > 0.5f) ? __expf(sv[i2].y - mnew) : 0.f;
                e.z = (mk[i2].z > 0.5f) ? __expf(sv[i2].z - mnew) : 0.f;
                e.w = (mk[i2].w > 0.5f) ? __expf(sv[i2].w - mnew) : 0.f;
                *(float4*)&row[quad*4 + i2*16] = e;
                csum += e.x + e.y + e.z + e.w;
            }
            csum += __shfl_xor(csum, 16);
            csum += __shfl_xor(csum, 32);
            if (quad == 0) {
                mst[w*16 + m16] = mnew;
                lst[w*16 + m16] = lst[w*16 + m16] * al + csum;
                alp[w*16 + m16] = al;
            }
        }
        asm volatile("" ::: "memory");
        {
            float alR[4];
            #pragma unroll
            for (int r = 0; r < 4; ++r) alR[r] = alp[w*16 + quad*4 + r];
            #pragma unroll
            for (int a = 0; a < 4; ++a)
                #pragma unroll
                for (int r = 0; r < 4; ++r) facc[a][r] *= alR[r];
            #pragma unroll
            for (int sub = 0; sub < 4; ++sub) {
                const float* spnp = &scw[m16 * 132 + sub * 32 + quad * 8];
                const float4 p0 = *(const float4*)spnp;
                const float4 p1 = *(const float4*)(spnp + 4);
                bf16x8 pa;
                pa[0] = (short)f2bf(p0.x); pa[1] = (short)f2bf(p0.y);
                pa[2] = (short)f2bf(p0.z); pa[3] = (short)f2bf(p0.w);
                pa[4] = (short)f2bf(p1.x); pa[5] = (short)f2bf(p1.y);
                pa[6] = (short)f2bf(p1.z); pa[7] = (short)f2bf(p1.w);
                const unsigned short* vp0 = vb + (size_t)m16 * SS + s0 + sub * 32 + quad * 8;
                #pragma unroll
                for (int a = 0; a < 4; ++a) {
                    const bf16x8 vfr = *(const bf16x8*)(vp0 + (size_t)(a * 16) * SS);
                    facc[a] = __builtin_amdgcn_mfma_f32_16x16x32_bf16(pa, vfr, facc[a], 0, 0, 0);
                }
            }
        }
        asm volatile("" ::: "memory");
    }
    float* po = part_O + (size_t)split * NND * HA;
    #pragma unroll
    for (int a = 0; a < 4; ++a)
        #pragma unroll
        for (int r = 0; r < 4; ++r) {
            const int row = quad*4 + r;
            if (row < nvalid)
                po[(size_t)(n0 + row) * HA + h * AA + a * 16 + m16] = facc[a][r];
        }
    if (quad == 0 && m16 < nvalid)
        part_ml[(size_t)split * NND * HH + (size_t)(n0 + m16) * HH + h] =
            make_float2(mst[w*16 + m16], lst[w*16 + m16]);
}

// ---------------------------------------------------------------------------
// Kernel 3c: combine split partials; emit gf = gate * feat as bf16
// ---------------------------------------------------------------------------
__global__ __launch_bounds__(256) void combine_kernel(
    const float* __restrict__ part_O, const float2* __restrict__ part_ml,
    const float* __restrict__ gate_ws, unsigned short* __restrict__ gf_bf)
{
    const size_t i = (size_t)blockIdx.x * 256 + threadIdx.x;
    const int n = (int)(i >> 9);
    const int c = (int)(i & (HA - 1));
    const int h = c >> 6;
    const float2 ml0 = part_ml[(size_t)n * HH + h];
    const float2 ml1 = part_ml[(size_t)NND * HH + (size_t)n * HH + h];
    const float m  = fmaxf(ml0.x, ml1.x);
    const float w0 = __expf(ml0.x - m);
    const float w1 = __expf(ml1.x - m);
    const float l  = ml0.y * w0 + ml1.y * w1;
    const float O  = part_O[i] * w0 + part_O[(size_t)NND * HA + i] * w1;
    gf_bf[i] = f2bf(gate_ws[i] * (O / (l + 1e-9f)));
}

// ---------------------------------------------------------------------------
// Kernel 4: MFMA back-projection + residual + LayerNorm. 16 rows/block.
// ---------------------------------------------------------------------------
__global__ __launch_bounds__(256) void back_ln_mfma(
    const unsigned short* __restrict__ gf_bf, const unsigned short* __restrict__ WbackT,
    const float* __restrict__ x, const float* __restrict__ bback,
    const float* __restrict__ gamma, const float* __restrict__ beta,
    float* __restrict__ out)
{
    __shared__ float nl[16][260];
    const int t = threadIdx.x, w = t >> 6, lane = t & 63;
    const int m16 = lane & 15, quad = lane >> 4;
    const int r0 = blockIdx.x * 16;
    const unsigned short* ap = gf_bf + (size_t)(r0 + m16) * HA + quad * 8;
    bf16x8 af[16];
    #pragma unroll
    for (int j = 0; j < 16; ++j) af[j] = *(const bf16x8*)(ap + j * 32);
    #pragma unroll
    for (int nt = 0; nt < 4; ++nt) {
        const int n0 = w * 64 + nt * 16;
        const unsigned short* bp = WbackT + (size_t)(n0 + m16) * HA + quad * 8;
        f32x4 d = (f32x4){0.f, 0.f, 0.f, 0.f};
        #pragma unroll
        for (int j = 0; j < 16; ++j)
            d = __builtin_amdgcn_mfma_f32_16x16x32_bf16(af[j], *(const bf16x8*)(bp + j * 32), d, 0, 0, 0);
        const float bb = bback[n0 + m16];
        #pragma unroll
        for (int r = 0; r < 4; ++r)
            nl[quad * 4 + r][n0 + m16] = d[r] + bb;
    }
    __syncthreads();
    const int row = t >> 4, c0 = t & 15;
    const float* xr = x + (size_t)(r0 + row) * IFZ;
    float yv[16];
    float s1 = 0.f, s2 = 0.f;
    #pragma unroll
    for (int j = 0; j < 16; ++j) {
        const float v = fmaf(1.41421356237309515f, xr[c0 + j*16], nl[row][c0 + j*16]);
        yv[j] = v; s1 += v; s2 += v * v;
    }
    #pragma unroll
    for (int off = 8; off >= 1; off >>= 1) {
        s1 += __shfl_xor(s1, off);
        s2 += __shfl_xor(s2, off);
    }
    const float mu  = s1 * (1.f / IFZ);
    const float var = s2 * (1.f / IFZ) - mu * mu;
    const float rv  = rsqrtf(var + 1e-5f);
    float* orow = out + (size_t)(r0 + row) * IFZ;
    #pragma unroll
    for (int j = 0; j < 16; ++j)
        orow[c0 + j*16] = (yv[j] - mu) * rv * gamma[c0 + j*16] + beta[c0 + j*16];
}

extern "C" void kernel_launch(void* const* d_in, const int* in_sizes, int n_in,
                              void* d_out, int out_size, void* d_ws, size_t ws_size,
                              hipStream_t stream) {
    const float* x     = (const float*)d_in[0];
    const float* emb   = (const float*)d_in[1];
    const void*  mraw  = d_in[2];
    const void*  braw  = d_in[3];
    const float* Wq    = (const float*)d_in[4];
    const float* Wk    = (const float*)d_in[5];
    const float* Wv    = (const float*)d_in[6];
    const float* Wg    = (const float*)d_in[7];
    const float* bg    = (const float*)d_in[8];
    const float* Wback = (const float*)d_in[9];
    const float* bback = (const float*)d_in[10];
    const float* gamma = (const float*)d_in[11];
    const float* beta  = (const float*)d_in[12];

    char* ws = (char*)d_ws;
    const size_t MB = 1048576;
    size_t off = 0;
    float*          mask_f  = (float*)(ws + off);  off += 16384;
    int*            seg     = (int*)(ws + off);    off += 16384;
    unsigned short* emb_bf  = (unsigned short*)(ws + off); off += 3*MB;      // 4096*384*2
    unsigned short* x_bf    = (unsigned short*)(ws + off); off += 1*MB;      // 2048*256*2
    unsigned short* WkT     = (unsigned short*)(ws + off); off += 393216;
    unsigned short* WvT     = (unsigned short*)(ws + off); off += 393216;
    unsigned short* WqT     = (unsigned short*)(ws + off); off += 262144;
    unsigned short* WgT     = (unsigned short*)(ws + off); off += 262144;
    unsigned short* WbackT  = (unsigned short*)(ws + off); off += 262144;
    unsigned short* k_bf    = (unsigned short*)(ws + off); off += 4*MB;
    unsigned short* v_bf    = (unsigned short*)(ws + off); off += 4*MB;
    unsigned short* vT_bf   = (unsigned short*)(ws + off); off += 4*MB;
    unsigned short* q_bf    = (unsigned short*)(ws + off); off += 2*MB;
    float*          gate_ws = (float*)(ws + off); off += 4*MB;
    unsigned short* gf_bf   = (unsigned short*)(ws + off); off += 2*MB;
    float*          part_O  = (float*)(ws + off); off += 8*MB;
    float2*         part_ml = (float2*)(ws + off); off += 262144;

    float* out        = (float*)d_out;
    float* out_logits = out + (size_t)NND * IFZ;

    hipLaunchKernelGGL(detect_norm, dim3(1), dim3(256), 0, stream, mraw, braw, mask_f, seg);
    hipLaunchKernelGGL(prep_kernel, dim3(704), dim3(256), 0, stream,
                       emb, x, Wk, Wv, Wq, Wg, Wback,
                       emb_bf, x_bf, WkT, WvT, WqT, WgT, WbackT);
    hipLaunchKernelGGL(kv_mfma, dim3(256, 2), dim3(256), 0, stream,
                       emb_bf, WkT, WvT, k_bf, v_bf);
    hipLaunchKernelGGL(transpose_v, dim3(16, 8, 4), dim3(256), 0, stream, v_bf, vT_bf);
    hipLaunchKernelGGL(qg_mfma, dim3(128, 4), dim3(256), 0, stream,
                       x_bf, WqT, WgT, bg, q_bf, gate_ws);
    hipLaunchKernelGGL(logits_kernel, dim3(128, 4, 4), dim3(256), 0, stream,
                       k_bf, q_bf, seg, out_logits);
    hipLaunchKernelGGL(attn_kernel, dim3(128, 4, 4), dim3(256), 0, stream,
                       k_bf, vT_bf, q_bf, mask_f, seg, part_O, part_ml);
    hipLaunchKernelGGL(combine_kernel, dim3((NND * HA) / 256), dim3(256), 0, stream,
                       part_O, part_ml, gate_ws, gf_bf);
    hipLaunchKernelGGL(back_ln_mfma, dim3(NND / 16), dim3(256), 0, stream,
                       gf_bf, WbackT, x, bback, gamma, beta, out);
}